// Round 12
// baseline (619.786 us; speedup 1.0000x reference)
//
#include <hip/hip_runtime.h>
#include <hip/hip_bf16.h>

using bf16 = __hip_bfloat16;
typedef __bf16 bf16x8v __attribute__((ext_vector_type(8)));
typedef float f32x4 __attribute__((ext_vector_type(4)));

#define BN_EPS 1e-5f

// ---------- dtype helpers ----------
__device__ __forceinline__ void stval(float* p, float v) { *p = v; }
__device__ __forceinline__ void stval(bf16* p, float v)  { *p = __float2bfloat16(v); }

__device__ __forceinline__ void gload_lds16(const void* g, void* l) {
    __builtin_amdgcn_global_load_lds(
        (const __attribute__((address_space(1))) unsigned int*)g,
        (__attribute__((address_space(3))) unsigned int*)l,
        16, 0, 0);
}

// bijective XCD swizzle over an arbitrary block count (m204)
__device__ __forceinline__ int xcd_swz(int orig, int nwg) {
    int q = nwg >> 3, r = nwg & 7;
    int xcd = orig & 7, idx = orig >> 3;
    return (xcd < r ? xcd * (q + 1) : r * (q + 1) + (xcd - r) * q) + idx;
}

#define MFMA_BF16 __builtin_amdgcn_mfma_f32_16x16x32_bf16

// =====================================================================
// GEMM1: 256x128 bf16 MFMA TN GEMM, BK=32, 8 waves (4m x 2n, 64x64 each),
// 2 blocks/CU (regs<=128 via launch_bounds(512,4); LDS 48KB), 2-phase
// n-split schedule with counted vmcnt, XCD swizzle, fused column stats.
// C[m][n] = sum_k A[m][k]*B[n][k]; M%256==0, N%128==0, K%32==0, K/32>=2.
// grid (N/128, M/256), nwg%8==0, block 512. Plain 64B-row LDS (m97 layout,
// conflict-free at BK=32 -- no swizzle needed).
// =====================================================================
template<typename TC>
__global__ __launch_bounds__(512, 4) void mfma_tn8c(
    const bf16* __restrict__ A, const bf16* __restrict__ B, TC* __restrict__ C,
    int M, int N, int K, float* __restrict__ ps, float* __restrict__ pq)
{
    __shared__ alignas(16) char lds[49152];   // A: 2x16KB @0, B: 2x8KB @32768
    const int NT = K >> 5;
    const int tid = threadIdx.x;
    const int lane = tid & 63;
    const int wv = tid >> 6;
    const int wm = wv >> 1;        // 0..3
    const int wn = wv & 1;         // 0..1

    // XCD swizzle (nwg % 8 == 0 here)
    const int nbx = gridDim.x;
    int flat = blockIdx.y * nbx + blockIdx.x;
    const int cpx = (nbx * gridDim.y) >> 3;
    flat = (flat & 7) * cpx + (flat >> 3);
    const int mtile = flat / nbx;
    const long m0 = (long)mtile * 256;
    const long n0 = (long)(flat % nbx) * 128;

    // staging: thread t covers 16B at LDS row t>>2, chunk t&3 (64B rows)
    const int trow = tid >> 2;          // 0..127
    const int tk   = (tid & 3) * 8;     // k-elem offset
    const bf16* Ar = A + (m0 + trow) * (long)K + tk;
    const bf16* Br = B + (n0 + trow) * (long)K + tk;
    char* ldsAt = (char*)lds + tid * 16;
    char* ldsBt = (char*)lds + 32768 + tid * 16;

    auto stage_a = [&](int bbuf, int kt) {   // 256 rows x 32k = 2 loads
        const bf16* g = Ar + (kt << 5);
        char* d = ldsAt + bbuf * 16384;
        gload_lds16(g, d);
        gload_lds16(g + ((long)K << 7), d + 8192);   // rows +128
    };
    auto stage_b = [&](int bbuf, int kt) {   // 128 rows x 32k = 1 load
        gload_lds16(Br + (kt << 5), ldsBt + bbuf * 8192);
    };

    const int fr = lane & 15, fc = lane >> 4;

    f32x4 acc[4][4];
#pragma unroll
    for (int m = 0; m < 4; ++m)
#pragma unroll
        for (int n = 0; n < 4; ++n) acc[m][n] = (f32x4){0.f, 0.f, 0.f, 0.f};

    // prologue: tiles 0,1 (6 loads)
    stage_a(0, 0); stage_b(0, 0); stage_a(1, 1); stage_b(1, 1);

    for (int T = 0; T < NT; ++T) {
        const int bb = T & 1;
        const char* Ard = (const char*)lds + bb * 16384 + (wm * 64 + fr) * 64 + fc * 16;
        const char* Brd = (const char*)lds + 32768 + bb * 8192 + (wn * 64 + fr) * 64 + fc * 16;

        // ---- phase 0: A frags + B n0,n1 ----
        if (T == 0)          { asm volatile("s_waitcnt vmcnt(3)" ::: "memory"); }
        else if (T < NT - 1) { asm volatile("s_waitcnt vmcnt(2)" ::: "memory"); }
        else                 { asm volatile("s_waitcnt vmcnt(0)" ::: "memory"); }
        __builtin_amdgcn_s_barrier();
        __builtin_amdgcn_sched_barrier(0);

        bf16x8v a[4];
#pragma unroll
        for (int m = 0; m < 4; ++m) a[m] = *(const bf16x8v*)(Ard + m * 1024);
        bf16x8v b0 = *(const bf16x8v*)(Brd);
        bf16x8v b1 = *(const bf16x8v*)(Brd + 1024);

        if (T >= 1 && T + 1 < NT) stage_b(bb ^ 1, T + 1);

        __builtin_amdgcn_s_setprio(1);
#pragma unroll
        for (int m = 0; m < 4; ++m) {
            acc[m][0] = MFMA_BF16(a[m], b0, acc[m][0], 0, 0, 0);
            acc[m][1] = MFMA_BF16(a[m], b1, acc[m][1], 0, 0, 0);
        }
        __builtin_amdgcn_s_setprio(0);

        // ---- phase 1: B n2,n3; stage A(T+2) into current buf (A-reads done) ----
        __builtin_amdgcn_s_barrier();
        __builtin_amdgcn_sched_barrier(0);

        bf16x8v b2 = *(const bf16x8v*)(Brd + 2048);
        bf16x8v b3 = *(const bf16x8v*)(Brd + 3072);

        if (T + 2 < NT) stage_a(bb, T + 2);

        __builtin_amdgcn_s_setprio(1);
#pragma unroll
        for (int m = 0; m < 4; ++m) {
            acc[m][2] = MFMA_BF16(a[m], b2, acc[m][2], 0, 0, 0);
            acc[m][3] = MFMA_BF16(a[m], b3, acc[m][3], 0, 0, 0);
        }
        __builtin_amdgcn_s_setprio(0);
    }

    // epilogue: C/D layout col=lane&15, row=(lane>>4)*4+reg
#pragma unroll
    for (int m = 0; m < 4; ++m) {
        long gr = m0 + wm * 64 + m * 16 + fc * 4;
#pragma unroll
        for (int n = 0; n < 4; ++n) {
            long gc = n0 + wn * 64 + n * 16 + fr;
            TC* cp = C + gr * N + gc;
#pragma unroll
            for (int r = 0; r < 4; ++r) stval(cp + (long)r * N, acc[m][n][r]);
        }
    }

    // fused column stats (sum/sumsq of bf16-rounded values) -> ps/pq[mtile][N]
    if (ps != nullptr) {
        __syncthreads();
        float* red = (float*)lds;   // 1024 floats
        float cs[4], cq[4];
#pragma unroll
        for (int n = 0; n < 4; ++n) {
            float s = 0.f, q = 0.f;
#pragma unroll
            for (int m = 0; m < 4; ++m)
#pragma unroll
                for (int r = 0; r < 4; ++r) {
                    float v = __bfloat162float(__float2bfloat16(acc[m][n][r]));
                    s += v; q += v * v;
                }
            s += __shfl_xor(s, 16, 64); s += __shfl_xor(s, 32, 64);
            q += __shfl_xor(q, 16, 64); q += __shfl_xor(q, 32, 64);
            cs[n] = s; cq[n] = q;
        }
        if (fc == 0) {
#pragma unroll
            for (int n = 0; n < 4; ++n) {
                int c = wn * 64 + n * 16 + fr;    // 0..127
                red[wm * 128 + c] = cs[n];
                red[512 + wm * 128 + c] = cq[n];
            }
        }
        __syncthreads();
        if (tid < 128) {
            float s = red[tid] + red[128 + tid] + red[256 + tid] + red[384 + tid];
            float q = red[512 + tid] + red[640 + tid] + red[768 + tid] + red[896 + tid];
            ps[(long)mtile * N + n0 + tid] = s;
            pq[(long)mtile * N + n0 + tid] = q;
        }
    }
}

// =====================================================================
// bf16 MFMA TN GEMM, 128x128 m97-structure + XCD swizzle + optional
// fused column stats (stats of the bf16-rounded output).
// =====================================================================
template<typename TC>
__global__ __launch_bounds__(256) void mfma_tn(
    const bf16* __restrict__ A, const bf16* __restrict__ B, TC* __restrict__ C,
    int M, int N, int K, float* __restrict__ ps, float* __restrict__ pq)
{
    __shared__ alignas(16) unsigned short As[128 * 32];
    __shared__ alignas(16) unsigned short Bs[128 * 32];

    const int tid = threadIdx.x;
    const int l = tid & 63;
    const int nwg = gridDim.x * gridDim.y;
    int s = xcd_swz(blockIdx.y * gridDim.x + blockIdx.x, nwg);
    const int by = s / gridDim.x, bx = s % gridDim.x;
    const long m0 = (long)by * 128;
    const long n0 = (long)bx * 128;
    const int wr = (tid >> 7) & 1;
    const int wc = (tid >> 6) & 1;

    const int off0 = tid * 16;
    const int row0 = off0 >> 6;
    const int kp0  = (off0 >> 4) & 3;
    const bf16* Ag0 = A + (m0 + row0) * (long)K + kp0 * 8;
    const bf16* Ag1 = A + (m0 + row0 + 64) * (long)K + kp0 * 8;
    const bf16* Bg0 = B + (n0 + row0) * (long)K + kp0 * 8;
    const bf16* Bg1 = B + (n0 + row0 + 64) * (long)K + kp0 * 8;
    char* Asl0 = (char*)As + off0;
    char* Asl1 = (char*)As + off0 + 4096;
    char* Bsl0 = (char*)Bs + off0;
    char* Bsl1 = (char*)Bs + off0 + 4096;

    f32x4 acc[4][4];
#pragma unroll
    for (int m = 0; m < 4; ++m)
#pragma unroll
        for (int n = 0; n < 4; ++n) acc[m][n] = (f32x4){0.f, 0.f, 0.f, 0.f};

    const int fr = l & 15;
    const int fc = l >> 4;
    int aoff[4], boff[4];
#pragma unroll
    for (int m = 0; m < 4; ++m) aoff[m] = ((wr * 64 + m * 16 + fr) * 4 + fc) * 16;
#pragma unroll
    for (int n = 0; n < 4; ++n) boff[n] = ((wc * 64 + n * 16 + fr) * 4 + fc) * 16;

    for (int k0 = 0; k0 < K; k0 += 32) {
        gload_lds16(Ag0 + k0, Asl0);
        gload_lds16(Ag1 + k0, Asl1);
        gload_lds16(Bg0 + k0, Bsl0);
        gload_lds16(Bg1 + k0, Bsl1);
        __syncthreads();

        bf16x8v af[4], bfr[4];
#pragma unroll
        for (int m = 0; m < 4; ++m) af[m]  = *(const bf16x8v*)((const char*)As + aoff[m]);
#pragma unroll
        for (int n = 0; n < 4; ++n) bfr[n] = *(const bf16x8v*)((const char*)Bs + boff[n]);
#pragma unroll
        for (int m = 0; m < 4; ++m)
#pragma unroll
            for (int n = 0; n < 4; ++n)
                acc[m][n] = MFMA_BF16(af[m], bfr[n], acc[m][n], 0, 0, 0);
        __syncthreads();
    }

#pragma unroll
    for (int m = 0; m < 4; ++m) {
        long gr = m0 + wr * 64 + m * 16 + fc * 4;
#pragma unroll
        for (int n = 0; n < 4; ++n) {
            long gc = n0 + wc * 64 + n * 16 + fr;
            TC* cp = C + gr * N + gc;
#pragma unroll
            for (int r = 0; r < 4; ++r) stval(cp + (long)r * N, acc[m][n][r]);
        }
    }

    if (ps != nullptr) {
        float* red = (float*)As;
        float cs[4], cq[4];
#pragma unroll
        for (int n = 0; n < 4; ++n) {
            float s2 = 0.f, q2 = 0.f;
#pragma unroll
            for (int m = 0; m < 4; ++m)
#pragma unroll
                for (int r = 0; r < 4; ++r) {
                    float v = __bfloat162float(__float2bfloat16(acc[m][n][r]));
                    s2 += v; q2 += v * v;
                }
            s2 += __shfl_xor(s2, 16, 64); s2 += __shfl_xor(s2, 32, 64);
            q2 += __shfl_xor(q2, 16, 64); q2 += __shfl_xor(q2, 32, 64);
            cs[n] = s2; cq[n] = q2;
        }
        if (fc == 0) {
#pragma unroll
            for (int n = 0; n < 4; ++n) {
                int c = wc * 64 + n * 16 + fr;
                red[wr * 128 + c] = cs[n];
                red[256 + wr * 128 + c] = cq[n];
            }
        }
        __syncthreads();
        if (tid < 128) {
            float sv = red[tid] + red[128 + tid];
            float qv = red[256 + tid] + red[384 + tid];
            ps[(long)by * N + n0 + tid] = sv;
            pq[(long)by * N + n0 + tid] = qv;
        }
    }
}

// =====================================================================
// split-K 128x128 TN with BN-affine+ReLU fused into A staging (reg-staged
// A, per-global-k affine), f32 partials Cp[z][M][N]. XCD-swizzled.
// Serves GEMM2 (z=4) and GEMM5 (z=8).
// =====================================================================
__global__ __launch_bounds__(256) void mfma_tn_skbn(
    const bf16* __restrict__ A, const bf16* __restrict__ B, float* __restrict__ Cp,
    int M, int N, int K, int KCH, const float* __restrict__ ta, const float* __restrict__ tc)
{
    __shared__ alignas(16) unsigned short As[128 * 32];
    __shared__ alignas(16) unsigned short Bs[128 * 32];

    const int tid = threadIdx.x;
    const int l = tid & 63;
    const int gxy = gridDim.x * gridDim.y;
    const int nwg = gxy * gridDim.z;
    int s = xcd_swz((blockIdx.z * gridDim.y + blockIdx.y) * gridDim.x + blockIdx.x, nwg);
    const int bz = s / gxy;
    const int rem = s % gxy;
    const int by = rem / gridDim.x, bx = rem % gridDim.x;
    const long m0 = (long)by * 128;
    const long n0 = (long)bx * 128;
    const int wr = (tid >> 7) & 1;
    const int wc = (tid >> 6) & 1;
    const int ksrt = bz * KCH;

    const int off0 = tid * 16;
    const int row0 = off0 >> 6;
    const int kp0  = (off0 >> 4) & 3;
    const bf16* Ag0 = A + (m0 + row0) * (long)K + kp0 * 8 + ksrt;
    const bf16* Ag1 = A + (m0 + row0 + 64) * (long)K + kp0 * 8 + ksrt;
    const bf16* Bg0 = B + (n0 + row0) * (long)K + kp0 * 8 + ksrt;
    const bf16* Bg1 = B + (n0 + row0 + 64) * (long)K + kp0 * 8 + ksrt;
    char* Asl0 = (char*)As + off0;
    char* Asl1 = (char*)As + off0 + 4096;
    char* Bsl0 = (char*)Bs + off0;
    char* Bsl1 = (char*)Bs + off0 + 4096;

    f32x4 acc[4][4];
#pragma unroll
    for (int m = 0; m < 4; ++m)
#pragma unroll
        for (int n = 0; n < 4; ++n) acc[m][n] = (f32x4){0.f, 0.f, 0.f, 0.f};

    const int fr = l & 15;
    const int fc = l >> 4;
    int aoff[4], boff[4];
#pragma unroll
    for (int m = 0; m < 4; ++m) aoff[m] = ((wr * 64 + m * 16 + fr) * 4 + fc) * 16;
#pragma unroll
    for (int n = 0; n < 4; ++n) boff[n] = ((wc * 64 + n * 16 + fr) * 4 + fc) * 16;

    for (int k0 = 0; k0 < KCH; k0 += 32) {
        gload_lds16(Bg0 + k0, Bsl0);
        gload_lds16(Bg1 + k0, Bsl1);

        union { bf16 h[8]; uint4 u; } r0, r1;
        r0.u = *(const uint4*)(Ag0 + k0);
        r1.u = *(const uint4*)(Ag1 + k0);
        const int kb = ksrt + k0 + kp0 * 8;
        float4 av0 = *(const float4*)(ta + kb);
        float4 av1 = *(const float4*)(ta + kb + 4);
        float4 cv0 = *(const float4*)(tc + kb);
        float4 cv1 = *(const float4*)(tc + kb + 4);
        float av[8] = {av0.x, av0.y, av0.z, av0.w, av1.x, av1.y, av1.z, av1.w};
        float cv[8] = {cv0.x, cv0.y, cv0.z, cv0.w, cv1.x, cv1.y, cv1.z, cv1.w};
#pragma unroll
        for (int j = 0; j < 8; ++j) {
            float v = fmaxf(fmaf(av[j], __bfloat162float(r0.h[j]), cv[j]), 0.f);
            r0.h[j] = __float2bfloat16(v);
            v = fmaxf(fmaf(av[j], __bfloat162float(r1.h[j]), cv[j]), 0.f);
            r1.h[j] = __float2bfloat16(v);
        }
        *(uint4*)Asl0 = r0.u;
        *(uint4*)Asl1 = r1.u;
        __syncthreads();

        bf16x8v af[4], bfr[4];
#pragma unroll
        for (int m = 0; m < 4; ++m) af[m]  = *(const bf16x8v*)((const char*)As + aoff[m]);
#pragma unroll
        for (int n = 0; n < 4; ++n) bfr[n] = *(const bf16x8v*)((const char*)Bs + boff[n]);
#pragma unroll
        for (int m = 0; m < 4; ++m)
#pragma unroll
            for (int n = 0; n < 4; ++n)
                acc[m][n] = MFMA_BF16(af[m], bfr[n], acc[m][n], 0, 0, 0);
        __syncthreads();
    }

    float* Cb = Cp + (long)bz * M * N;
#pragma unroll
    for (int m = 0; m < 4; ++m) {
        long gr = m0 + wr * 64 + m * 16 + fc * 4;
#pragma unroll
        for (int n = 0; n < 4; ++n) {
            long gc = n0 + wc * 64 + n * 16 + fr;
            float* cp = Cb + gr * N + gc;
#pragma unroll
            for (int r = 0; r < 4; ++r) cp[(long)r * N] = acc[m][n][r];
        }
    }
}

// =====================================================================
// objin einsum as MFMA: per (b,h), C[32 t][256 c] = attnP . xP^T, K=224.
// =====================================================================
__global__ __launch_bounds__(256) void objmm_k(
    const bf16* __restrict__ attnP, const bf16* __restrict__ xP, bf16* __restrict__ objinT)
{
    __shared__ alignas(16) unsigned short As[32 * 32];
    __shared__ alignas(16) unsigned short Bs[256 * 32];
    const int tid = threadIdx.x, lane = tid & 63, wv = tid >> 6;
    const int b = blockIdx.x >> 3, h = blockIdx.x & 7;
    const bf16* Ab = attnP + ((long)(b * 256 + h * 32)) * 224;
    const bf16* Bb = xP + ((long)(b * 2048 + h * 256)) * 224;
    const int fr = lane & 15, fc = lane >> 4;
    const int srow = tid >> 2, schk = tid & 3;

    f32x4 acc[2][4];
#pragma unroll
    for (int m = 0; m < 2; ++m)
#pragma unroll
        for (int n = 0; n < 4; ++n) acc[m][n] = (f32x4){0.f, 0.f, 0.f, 0.f};

    for (int k0 = 0; k0 < 224; k0 += 32) {
        if (wv < 2)
            gload_lds16(Ab + (long)srow * 224 + schk * 8 + k0, (char*)As + tid * 16);
#pragma unroll
        for (int j = 0; j < 4; ++j)
            gload_lds16(Bb + (long)(j * 64 + srow) * 224 + schk * 8 + k0,
                        (char*)Bs + j * 4096 + tid * 16);
        __syncthreads();

        bf16x8v af[2], bfr[4];
#pragma unroll
        for (int m = 0; m < 2; ++m)
            af[m] = *(const bf16x8v*)((const char*)As + (m * 16 + fr) * 64 + fc * 16);
#pragma unroll
        for (int n = 0; n < 4; ++n)
            bfr[n] = *(const bf16x8v*)((const char*)Bs + (wv * 64 + n * 16 + fr) * 64 + fc * 16);
#pragma unroll
        for (int m = 0; m < 2; ++m)
#pragma unroll
            for (int n = 0; n < 4; ++n)
                acc[m][n] = MFMA_BF16(af[m], bfr[n], acc[m][n], 0, 0, 0);
        __syncthreads();
    }

#pragma unroll
    for (int m = 0; m < 2; ++m) {
        long gr = (long)b * 32 + m * 16 + fc * 4;
#pragma unroll
        for (int n = 0; n < 4; ++n) {
            long gc = (long)h * 256 + wv * 64 + n * 16 + fr;
            bf16* cp = objinT + gr * 2048 + gc;
#pragma unroll
            for (int r = 0; r < 4; ++r) cp[(long)r * 2048] = __float2bfloat16(acc[m][n][r]);
        }
    }
}

// ---------- fold GEMM2 split-K partials (x4) + row L2-norm; blocks >= 3136
// additionally fold the pooled-branch split-K output (merged skreduce) ----------
__global__ __launch_bounds__(256) void foldnorm_k(const float* __restrict__ p,
    float* __restrict__ z, float* __restrict__ invn,
    const float* __restrict__ skp2, float* __restrict__ out)
{
    if (blockIdx.x >= 3136) {
        int i = (blockIdx.x - 3136) * 256 + threadIdx.x;   // 16384 total
        float s = 0.f;
        for (int pz = 0; pz < 32; ++pz) s += skp2[(long)pz * 16384 + i];
        int m = i >> 6, n = i & 63;
        out[m + n * 256] = s;
        return;
    }
    int j = blockIdx.x * 4 + (threadIdx.x >> 6);
    int lane = threadIdx.x & 63;
    long off = (long)j * 256 + lane * 4;
    float4 a = *(const float4*)(p + off);
    float4 b = *(const float4*)(p + 3211264L + off);
    float4 c = *(const float4*)(p + 2 * 3211264L + off);
    float4 d = *(const float4*)(p + 3 * 3211264L + off);
    float4 s;
    s.x = (a.x + b.x) + (c.x + d.x);
    s.y = (a.y + b.y) + (c.y + d.y);
    s.z = (a.z + b.z) + (c.z + d.z);
    s.w = (a.w + b.w) + (c.w + d.w);
    *(float4*)(z + off) = s;
    float q = s.x * s.x + s.y * s.y + s.z * s.z + s.w * s.w;
#pragma unroll
    for (int off2 = 32; off2; off2 >>= 1) q += __shfl_xor(q, off2, 64);
    if (lane == 0) invn[j] = 1.f / fmaxf(sqrtf(q), 1e-12f);
}

// ---------- fold GEMM5 split-K partials (x8) + reorder -> out[b*8192+q*32+t] ----------
__global__ __launch_bounds__(256) void foldout_k(const float* __restrict__ p, float* __restrict__ out)
{
    int o = blockIdx.x * 256 + threadIdx.x;
    int b = o >> 13, rem = o & 8191, q = rem >> 5, tt = rem & 31;
    long base = ((long)(b * 32 + tt)) * 256 + q;
    float s = 0.f;
#pragma unroll
    for (int z = 0; z < 8; ++z) s += p[(long)z * 524288 + base];
    out[o] = s;
}

// =====================================================================
// merged prep: blocks [0,9216) convert the 4 weight matrices f32->bf16;
// blocks [9216, 9216+2048) pack x -> XT, xP (padded), xpT.
// =====================================================================
__global__ __launch_bounds__(256) void prep_k(
    const float* __restrict__ w1, const float* __restrict__ w2,
    const float* __restrict__ w3, const float* __restrict__ w4,
    bf16* __restrict__ o1, bf16* __restrict__ o2,
    bf16* __restrict__ o3, bf16* __restrict__ o4,
    const float* __restrict__ x, bf16* __restrict__ XT,
    bf16* __restrict__ xP, float* __restrict__ xpT)
{
    __shared__ unsigned short tile[196 * 66 + 4];
    __shared__ float pp[64];
    const int t = threadIdx.x;

    if (blockIdx.x < 9216) {
        const long L1 = 8388608, L2 = 1048576;
        long i = ((long)blockIdx.x * 256 + t) * 8;
        const float* src; bf16* dst; long e;
        if (i < L1)             { src = w1; dst = o1; e = i; }
        else if (i < L1 + L2)   { src = w2; dst = o2; e = i - L1; }
        else if (i < 2*L1 + L2) { src = w3; dst = o3; e = i - L1 - L2; }
        else                    { src = w4; dst = o4; e = i - 2*L1 - L2; }
        float4 v0 = *(const float4*)(src + e);
        float4 v1 = *(const float4*)(src + e + 4);
        union { bf16 h[8]; uint4 u; } r;
        r.h[0] = __float2bfloat16(v0.x); r.h[1] = __float2bfloat16(v0.y);
        r.h[2] = __float2bfloat16(v0.z); r.h[3] = __float2bfloat16(v0.w);
        r.h[4] = __float2bfloat16(v1.x); r.h[5] = __float2bfloat16(v1.y);
        r.h[6] = __float2bfloat16(v1.z); r.h[7] = __float2bfloat16(v1.w);
        *(uint4*)(dst + e) = r.u;
        return;
    }

    const int bid = blockIdx.x - 9216;
    const int b = bid >> 5, c0 = (bid & 31) * 64;
    const int wvi = t >> 6, lane = t & 63;

    for (int p = 0; p < 16; ++p) {
        int c = p * 4 + wvi;
        const float* row = x + ((long)b * 2048 + c0 + c) * 196;
        float v0 = row[lane];
        float v1 = row[lane + 64];
        float v2 = row[lane + 128];
        float v3 = (lane < 4) ? row[lane + 192] : 0.f;
        bf16 h0 = __float2bfloat16(v0);
        bf16 h1 = __float2bfloat16(v1);
        bf16 h2 = __float2bfloat16(v2);
        bf16 h3 = __float2bfloat16(v3);
        tile[lane * 66 + c]         = *(unsigned short*)&h0;
        tile[(lane + 64) * 66 + c]  = *(unsigned short*)&h1;
        tile[(lane + 128) * 66 + c] = *(unsigned short*)&h2;
        if (lane < 4) tile[(lane + 192) * 66 + c] = *(unsigned short*)&h3;
        float s = v0 + v1 + v2 + v3;
#pragma unroll
        for (int off = 32; off; off >>= 1) s += __shfl_xor(s, off, 64);
        if (lane == 0) pp[c] = s;
    }
    __syncthreads();
    if (t < 64) xpT[(c0 + t) * 64 + b] = pp[t] * (1.f / 196.f);

    for (int u = t; u < 196 * 8; u += 256) {
        int l = u >> 3, cc = u & 7;
        const unsigned short* sp = &tile[l * 66 + cc * 8];
        uint4 r;
        r.x = *(const unsigned int*)(sp);
        r.y = *(const unsigned int*)(sp + 2);
        r.z = *(const unsigned int*)(sp + 4);
        r.w = *(const unsigned int*)(sp + 6);
        *(uint4*)(&XT[((long)b * 196 + l) * 2048 + c0 + cc * 8]) = r;
    }

    for (int u = t; u < 64 * 28; u += 256) {
        int c = u / 28, ch = u % 28;
        int l0 = ch * 8;
        union { unsigned short h[8]; uint4 v; } r;
#pragma unroll
        for (int e = 0; e < 8; ++e) {
            int ll = l0 + e;
            r.h[e] = (ll < 196) ? tile[ll * 66 + c] : (unsigned short)0;
        }
        *(uint4*)(xP + ((long)b * 2048 + c0 + c) * 224 + l0) = r.v;
    }
}

// ---------- fold stat partials -> per-channel affine ----------
__global__ __launch_bounds__(256) void colstat2_k(const float* __restrict__ ps, const float* __restrict__ pq,
    int P, float invN, const float* __restrict__ g, const float* __restrict__ be,
    float* __restrict__ ta, float* __restrict__ tc)
{
    int c = blockIdx.x * 256 + threadIdx.x;
    float s = 0.f, q = 0.f;
    for (int p = 0; p < P; ++p) { s += ps[(long)p * 4096 + c]; q += pq[(long)p * 4096 + c]; }
    float mu  = s * invN;
    float var = q * invN - mu * mu;
    float a   = g[c] * rsqrtf(var + BN_EPS);
    ta[c] = a;
    tc[c] = be[c] - mu * a;
}

// ---------- softmax -> attnP[b*256+q][224] bf16 (zero-padded) ----------
__global__ __launch_bounds__(256) void softmax2_k(const float* __restrict__ z,
    const float* __restrict__ invn, bf16* __restrict__ attnP)
{
    int row  = blockIdx.x * 4 + (threadIdx.x >> 6);
    int lane = threadIdx.x & 63;
    int b = row >> 8, q = row & 255;
    float v[4];
    float mx = -INFINITY;
#pragma unroll
    for (int i = 0; i < 4; ++i) {
        int l = lane + 64 * i;
        if (l < 196) {
            int j = b * 196 + l;
            v[i] = z[(long)j * 256 + q] * invn[j];
        } else v[i] = -INFINITY;
        mx = fmaxf(mx, v[i]);
    }
#pragma unroll
    for (int off = 32; off; off >>= 1) mx = fmaxf(mx, __shfl_xor(mx, off, 64));
    float s = 0.f;
#pragma unroll
    for (int i = 0; i < 4; ++i) {
        v[i] = (lane + 64 * i < 196) ? __expf(v[i] - mx) : 0.f;
        s += v[i];
    }
#pragma unroll
    for (int off = 32; off; off >>= 1) s += __shfl_xor(s, off, 64);
    float is = 1.f / s;
    bf16* rp = attnP + (long)row * 224;
#pragma unroll
    for (int i = 0; i < 4; ++i) {
        int l = lane + 64 * i;
        if (l < 196) rp[l] = __float2bfloat16(v[i] * is);
        else if (l < 224) rp[l] = __float2bfloat16(0.f);
    }
}

// =====================================================================
// split-K f32 GEMM for the tiny pooled branch
// =====================================================================
template<bool TRANS>
__global__ __launch_bounds__(256) void gemmsk_k(
    const float* __restrict__ A, const float* __restrict__ B, float* __restrict__ Cp,
    int M, int N, int K, int lda, int ldbk, int KCH,
    const float* __restrict__ tra, const float* __restrict__ trc)
{
    constexpr int BM = 64, BN = 64, BK = 16;
    __shared__ float As[BK][BM + 4];
    __shared__ float Bs[BK][BN + 4];

    const int tid = threadIdx.x;
    const int m0 = blockIdx.y * BM;
    const int ks = blockIdx.z * KCH;
    const int ke = min(K, ks + KCH);

    const int tIdm = tid / 16;
    const int tIdn = tid % 16;
    const int aK  = tid % BK;
    const int aM0 = tid / BK;
    const int bN  = tid % BN;
    const int bK0 = tid / BN;

    float acc[4][4];
#pragma unroll
    for (int u = 0; u < 4; ++u)
#pragma unroll
        for (int v = 0; v < 4; ++v) acc[u][v] = 0.f;

    for (int k0 = ks; k0 < ke; k0 += BK) {
#pragma unroll
        for (int i = 0; i < 4; ++i) {
            int m = aM0 + 16 * i;
            int gk = k0 + aK, gm = m0 + m;
            float v = 0.f;
            if (gk < ke && gm < M) v = A[(long)gm * lda + gk];
            As[aK][m] = v;
        }
#pragma unroll
        for (int i = 0; i < 4; ++i) {
            int kk = bK0 + 4 * i;
            int gk = k0 + kk;
            float v = 0.f;
            if (gk < ke && bN < N) {
                v = B[(long)gk * ldbk + bN];
                if (TRANS) v = fmaxf(tra[gk] * v + trc[gk], 0.f);
            }
            Bs[kk][bN] = v;
        }
        __syncthreads();
#pragma unroll
        for (int kk = 0; kk < BK; ++kk) {
            float a[4], b[4];
#pragma unroll
            for (int u = 0; u < 4; ++u) a[u] = As[kk][tIdm * 4 + u];
#pragma unroll
            for (int v = 0; v < 4; ++v) b[v] = Bs[kk][tIdn * 4 + v];
#pragma unroll
            for (int u = 0; u < 4; ++u)
#pragma unroll
                for (int v = 0; v < 4; ++v)
                    acc[u][v] = fmaf(a[u], b[v], acc[u][v]);
        }
        __syncthreads();
    }

    float* Cb = Cp + (long)blockIdx.z * M * N;
#pragma unroll
    for (int u = 0; u < 4; ++u) {
        int gm = m0 + tIdm * 4 + u;
        if (gm >= M) continue;
#pragma unroll
        for (int v = 0; v < 4; ++v) {
            int gn = tIdn * 4 + v;
            if (gn < N) Cb[(long)gm * N + gn] = acc[u][v];
        }
    }
}

// ---------- merged split-K fold + BN stats for pooled h1 [4096][64] ----------
__global__ __launch_bounds__(256) void skbn_k(const float* __restrict__ Cp,
    const float* __restrict__ g, const float* __restrict__ be,
    float* __restrict__ h1, float* __restrict__ ta, float* __restrict__ tc)
{
    int o = blockIdx.x * 4 + (threadIdx.x >> 6);
    int b = threadIdx.x & 63;
    float s = 0.f;
#pragma unroll
    for (int p = 0; p < 16; ++p) s += Cp[(long)p * 262144 + o * 64 + b];
    h1[o * 64 + b] = s;
    float s1 = s, s2 = s * s;
#pragma unroll
    for (int off = 32; off; off >>= 1) {
        s1 += __shfl_down(s1, off, 64);
        s2 += __shfl_down(s2, off, 64);
    }
    if (b == 0) {
        float mu  = s1 * (1.f / 64.f);
        float var = s2 * (1.f / 64.f) - mu * mu;
        float a   = g[o] * rsqrtf(var + BN_EPS);
        ta[o] = a;
        tc[o] = be[o] - mu * a;
    }
}

extern "C" void kernel_launch(void* const* d_in, const int* in_sizes, int n_in,
                              void* d_out, int out_size, void* d_ws, size_t ws_size,
                              hipStream_t stream)
{
    const float* x    = (const float*)d_in[0];
    const float* pW1  = (const float*)d_in[1];
    const float* pG1  = (const float*)d_in[2];
    const float* pB1  = (const float*)d_in[3];
    const float* pW2  = (const float*)d_in[4];
    const float* ppW1 = (const float*)d_in[5];
    const float* ppG1 = (const float*)d_in[6];
    const float* ppB1 = (const float*)d_in[7];
    const float* ppW2 = (const float*)d_in[8];
    const float* poW1 = (const float*)d_in[9];
    const float* poG1 = (const float*)d_in[10];
    const float* poB1 = (const float*)d_in[11];
    const float* poW2 = (const float*)d_in[12];
    float* out = (float*)d_out;
    (void)in_sizes; (void)n_in; (void)out_size; (void)ws_size;

    char* w = (char*)d_ws;
    auto alloc = [&](size_t bytes) -> char* {
        char* p = w; w += (bytes + 255) & ~(size_t)255; return p;
    };
    bf16* ppW1b = (bf16*)alloc((size_t)4096 * 2048 * 2);
    bf16* ppW2b = (bf16*)alloc((size_t)256 * 4096 * 2);
    bf16* poW1b = (bf16*)alloc((size_t)4096 * 2048 * 2);
    bf16* poW2b = (bf16*)alloc((size_t)256 * 4096 * 2);
    char* region1 = alloc((size_t)12544 * 2048 * 2);     // XT; later skpG2/attnP/objinT/hobjT
    bf16*  XT     = (bf16*)region1;
    float* skpG2  = (float*)region1;     // 4 x 12544 x 256 x 4 == region1 size
    bf16*  attnP  = (bf16*)region1;
    bf16*  objinT = (bf16*)(region1 + 12845056);
    bf16*  hobjT  = (bf16*)(region1 + 12845056 + 8388608);
    bf16* xP     = (bf16*)alloc((size_t)64 * 2048 * 224 * 2);
    bf16* hfeatT = (bf16*)alloc((size_t)12544 * 4096 * 2);
    float* zfeatT = (float*)alloc((size_t)12544 * 256 * 4);
    float* ps    = (float*)alloc((size_t)49 * 4096 * 4);
    float* pq    = (float*)alloc((size_t)49 * 4096 * 4);
    float* invn  = (float*)alloc((size_t)12544 * 4);
    float* a2    = (float*)alloc(4096 * 4);
    float* c2    = (float*)alloc(4096 * 4);
    float* a3    = (float*)alloc(4096 * 4);
    float* c3    = (float*)alloc(4096 * 4);
    float* xpT   = (float*)alloc((size_t)2048 * 64 * 4);
    float* h1    = (float*)alloc((size_t)4096 * 64 * 4);
    float* a1    = (float*)alloc(4096 * 4);
    float* c1    = (float*)alloc(4096 * 4);
    float* skp1  = (float*)alloc((size_t)16 * 4096 * 64 * 4);
    float* skp2  = (float*)alloc((size_t)32 * 256 * 64 * 4);
    float* skp5  = (float*)alloc((size_t)8 * 2048 * 256 * 4);

    // ---- merged weight converts + input pack (one launch) ----
    prep_k<<<9216 + 2048, 256, 0, stream>>>(ppW1, ppW2, poW1, poW2,
                                            ppW1b, ppW2b, poW1b, poW2b,
                                            x, XT, xP, xpT);

    // ---- pooled branch (split-K f32, merged fold+stats) ----
    gemmsk_k<false><<<dim3(1, 64, 16), 256, 0, stream>>>(
        pW1, xpT, skp1, 4096, 64, 2048, 2048, 64, 128, nullptr, nullptr);
    skbn_k<<<1024, 256, 0, stream>>>(skp1, pG1, pB1, h1, a1, c1);
    gemmsk_k<true><<<dim3(1, 4, 32), 256, 0, stream>>>(
        pW2, h1, skp2, 256, 64, 4096, 4096, 64, 128, a1, c1);

    // ---- GEMM1 (256x128, BK=32, 2 blocks/CU) + fused column stats ----
    mfma_tn8c<bf16><<<dim3(32, 49), 512, 0, stream>>>(XT, ppW1b, hfeatT, 12544, 4096, 2048, ps, pq);
    colstat2_k<<<16, 256, 0, stream>>>(ps, pq, 49, 1.f / 12544.f, ppG1, ppB1, a2, c2);

    // ---- GEMM2: split-K x4, fused BN+ReLU on A; fold + row-norm (+ pooled-out fold) ----
    mfma_tn_skbn<<<dim3(2, 98, 4), 256, 0, stream>>>(
        hfeatT, ppW2b, skpG2, 12544, 256, 4096, 1024, a2, c2);
    foldnorm_k<<<3136 + 64, 256, 0, stream>>>(skpG2, zfeatT, invn, skp2, out);

    // ---- softmax -> attnP ----
    softmax2_k<<<4096, 256, 0, stream>>>(zfeatT, invn, attnP);

    // ---- objin einsum via MFMA ----
    objmm_k<<<512, 256, 0, stream>>>(attnP, xP, objinT);

    // ---- GEMM4 + fused column stats ----
    mfma_tn<bf16><<<dim3(32, 16), 256, 0, stream>>>(objinT, poW1b, hobjT, 2048, 4096, 2048, ps, pq);
    colstat2_k<<<16, 256, 0, stream>>>(ps, pq, 16, 1.f / 2048.f, poG1, poB1, a3, c3);

    // ---- GEMM5 (split-K x8, fused BN+ReLU on A) + fold/reorder ----
    mfma_tn_skbn<<<dim3(2, 16, 8), 256, 0, stream>>>(
        hobjT, poW2b, skp5, 2048, 256, 4096, 512, a3, c3);
    foldout_k<<<2048, 256, 0, stream>>>(skp5, out + 16384);
}

// Round 13
// 600.236 us; speedup vs baseline: 1.0326x; 1.0326x over previous
//
#include <hip/hip_runtime.h>
#include <hip/hip_bf16.h>

using bf16 = __hip_bfloat16;
typedef __bf16 bf16x8v __attribute__((ext_vector_type(8)));
typedef float f32x4 __attribute__((ext_vector_type(4)));

#define BN_EPS 1e-5f

// ---------- dtype helpers ----------
__device__ __forceinline__ void stval(float* p, float v) { *p = v; }
__device__ __forceinline__ void stval(bf16* p, float v)  { *p = __float2bfloat16(v); }

__device__ __forceinline__ void gload_lds16(const void* g, void* l) {
    __builtin_amdgcn_global_load_lds(
        (const __attribute__((address_space(1))) unsigned int*)g,
        (__attribute__((address_space(3))) unsigned int*)l,
        16, 0, 0);
}

// bijective XCD swizzle over an arbitrary block count (m204)
__device__ __forceinline__ int xcd_swz(int orig, int nwg) {
    int q = nwg >> 3, r = nwg & 7;
    int xcd = orig & 7, idx = orig >> 3;
    return (xcd < r ? xcd * (q + 1) : r * (q + 1) + (xcd - r) * q) + idx;
}

#define MFMA_BF16 __builtin_amdgcn_mfma_f32_16x16x32_bf16

// =====================================================================
// GEMM1: 256x256 bf16 MFMA TN GEMM, 2-phase schedule (8 waves, BK=64,
// counted vmcnt(4), XOR-swizzled LDS reads, XCD swizzle) + fused
// per-column sum/sumsq partials of the bf16-rounded output.
// [round-8/10 verified schedule: 229us, MfmaUtil 40%, 0 conflicts.
//  Round 4/7/9 brackets: finer phase-split or fewer barriers both lose.
//  Round 11: 2 blocks/CU at 256x128 = same MfmaUtil (LDS-BW roof), more HBM.]
// =====================================================================
template<typename TC>
__global__ __launch_bounds__(512, 2) void mfma_tn8(
    const bf16* __restrict__ A, const bf16* __restrict__ B, TC* __restrict__ C,
    int M, int N, int K, float* __restrict__ ps, float* __restrict__ pq)
{
    __shared__ char lds[131072];   // 2 bufs x (A 32KB + B 32KB)
    const int NT = K >> 6;
    const int tid = threadIdx.x;
    const int lane = tid & 63;
    const int wv = tid >> 6;
    const int wm = wv >> 2;        // 0..1
    const int wn = wv & 3;         // 0..3

    // XCD swizzle (nwg % 8 == 0 here)
    const int nbx = gridDim.x;
    int flat = blockIdx.y * nbx + blockIdx.x;
    const int cpx = (nbx * gridDim.y) >> 3;
    flat = (flat & 7) * cpx + (flat >> 3);
    const int mtile = flat / nbx;
    const long m0 = (long)mtile * 256;
    const long n0 = (long)(flat % nbx) * 256;

    // staging: LDS linear; pre-swizzled global k-offset (rule 21)
    const int trow = tid >> 3;
    const int ks = (((tid & 7) ^ ((tid >> 3) & 7)) << 3);
    const bf16* Arow0 = A + (m0 + trow) * (long)K + ks;
    const bf16* Brow0 = B + (n0 + trow) * (long)K + ks;
    char* ldsA = (char*)lds + tid * 16;
    char* ldsB = (char*)lds + 32768 + tid * 16;

    auto stage_a = [&](int bbuf, int kt) {
        const bf16* g = Arow0 + ((long)kt << 6);
        char* d = ldsA + (bbuf << 16);
        gload_lds16(g, d);
        gload_lds16(g + ((long)K << 6),  d + 8192);
        gload_lds16(g + ((long)K << 7),  d + 16384);
        gload_lds16(g + 192L * (long)K,  d + 24576);
    };
    auto stage_b = [&](int bbuf, int kt) {
        const bf16* g = Brow0 + ((long)kt << 6);
        char* d = ldsB + (bbuf << 16);
        gload_lds16(g, d);
        gload_lds16(g + ((long)K << 6),  d + 8192);
        gload_lds16(g + ((long)K << 7),  d + 16384);
        gload_lds16(g + 192L * (long)K,  d + 24576);
    };

    // fragment read offsets (swizzled)
    const int fr = lane & 15, fc = lane >> 4;
    const int ca0 = ((fc ^ (fr & 7)) << 4);
    const int ca1 = (((4 + fc) ^ (fr & 7)) << 4);

    f32x4 acc[8][4];
#pragma unroll
    for (int m = 0; m < 8; ++m)
#pragma unroll
        for (int n = 0; n < 4; ++n) acc[m][n] = (f32x4){0.f, 0.f, 0.f, 0.f};

    // prologue: tiles 0 and 1
    stage_a(0, 0); stage_b(0, 0); stage_a(1, 1); stage_b(1, 1);

    for (int T = 0; T < NT; ++T) {
        const int bb = T & 1;
        const char* Ard = (const char*)lds + (bb << 16) + (wm * 128 + fr) * 128;
        const char* Brd = (const char*)lds + (bb << 16) + 32768 + (wn * 64 + fr) * 128;

        // ---- phase 0 ----
        if (T == 0)          { asm volatile("s_waitcnt vmcnt(8)" ::: "memory"); }
        else if (T < NT - 1) { asm volatile("s_waitcnt vmcnt(4)" ::: "memory"); }
        else                 { asm volatile("s_waitcnt vmcnt(0)" ::: "memory"); }
        __builtin_amdgcn_s_barrier();
        __builtin_amdgcn_sched_barrier(0);

        bf16x8v a0[8], a1[8];
#pragma unroll
        for (int m = 0; m < 8; ++m) {
            a0[m] = *(const bf16x8v*)(Ard + m * 2048 + ca0);
            a1[m] = *(const bf16x8v*)(Ard + m * 2048 + ca1);
        }
        bf16x8v b00 = *(const bf16x8v*)(Brd + ca0);
        bf16x8v b01 = *(const bf16x8v*)(Brd + ca1);
        bf16x8v b10 = *(const bf16x8v*)(Brd + 2048 + ca0);
        bf16x8v b11 = *(const bf16x8v*)(Brd + 2048 + ca1);

        if (T >= 1 && T + 1 < NT) stage_b(bb ^ 1, T + 1);

        __builtin_amdgcn_s_setprio(1);
#pragma unroll
        for (int m = 0; m < 8; ++m) {
            acc[m][0] = MFMA_BF16(a0[m], b00, acc[m][0], 0, 0, 0);
            acc[m][0] = MFMA_BF16(a1[m], b01, acc[m][0], 0, 0, 0);
            acc[m][1] = MFMA_BF16(a0[m], b10, acc[m][1], 0, 0, 0);
            acc[m][1] = MFMA_BF16(a1[m], b11, acc[m][1], 0, 0, 0);
        }
        __builtin_amdgcn_s_setprio(0);

        // ---- phase 1 ----
        __builtin_amdgcn_s_barrier();
        __builtin_amdgcn_sched_barrier(0);

        bf16x8v b20 = *(const bf16x8v*)(Brd + 2 * 2048 + ca0);
        bf16x8v b21 = *(const bf16x8v*)(Brd + 2 * 2048 + ca1);
        bf16x8v b30 = *(const bf16x8v*)(Brd + 3 * 2048 + ca0);
        bf16x8v b31 = *(const bf16x8v*)(Brd + 3 * 2048 + ca1);

        if (T + 2 < NT) stage_a(bb, T + 2);

        __builtin_amdgcn_s_setprio(1);
#pragma unroll
        for (int m = 0; m < 8; ++m) {
            acc[m][2] = MFMA_BF16(a0[m], b20, acc[m][2], 0, 0, 0);
            acc[m][2] = MFMA_BF16(a1[m], b21, acc[m][2], 0, 0, 0);
            acc[m][3] = MFMA_BF16(a0[m], b30, acc[m][3], 0, 0, 0);
            acc[m][3] = MFMA_BF16(a1[m], b31, acc[m][3], 0, 0, 0);
        }
        __builtin_amdgcn_s_setprio(0);
    }

    // epilogue: C/D layout col=lane&15, row=(lane>>4)*4+reg
#pragma unroll
    for (int m = 0; m < 8; ++m) {
        long gr = m0 + wm * 128 + m * 16 + fc * 4;
#pragma unroll
        for (int n = 0; n < 4; ++n) {
            long gc = n0 + wn * 64 + n * 16 + fr;
            TC* cp = C + gr * N + gc;
#pragma unroll
            for (int r = 0; r < 4; ++r) stval(cp + (long)r * N, acc[m][n][r]);
        }
    }

    // fused column stats (sum/sumsq of bf16-rounded values) -> ps/pq[mtile][N]
    if (ps != nullptr) {
        __syncthreads();
        float* red = (float*)lds;
        float cs[4], cq[4];
#pragma unroll
        for (int n = 0; n < 4; ++n) {
            float s = 0.f, q = 0.f;
#pragma unroll
            for (int m = 0; m < 8; ++m)
#pragma unroll
                for (int r = 0; r < 4; ++r) {
                    float v = __bfloat162float(__float2bfloat16(acc[m][n][r]));
                    s += v; q += v * v;
                }
            s += __shfl_xor(s, 16, 64); s += __shfl_xor(s, 32, 64);
            q += __shfl_xor(q, 16, 64); q += __shfl_xor(q, 32, 64);
            cs[n] = s; cq[n] = q;
        }
        if (fc == 0) {
#pragma unroll
            for (int n = 0; n < 4; ++n) {
                red[wv * 64 + n * 16 + fr] = cs[n];
                red[512 + wv * 64 + n * 16 + fr] = cq[n];
            }
        }
        __syncthreads();
        if (tid < 256) {
            int c = tid, wnn = c >> 6, idx = c & 63;
            float s = red[wnn * 64 + idx] + red[(4 + wnn) * 64 + idx];
            float q = red[512 + wnn * 64 + idx] + red[512 + (4 + wnn) * 64 + idx];
            ps[(long)mtile * N + n0 + c] = s;
            pq[(long)mtile * N + n0 + c] = q;
        }
    }
}

// =====================================================================
// bf16 MFMA TN GEMM, 128x128 m97-structure + XCD swizzle + optional
// fused column stats (stats of the bf16-rounded output).
// =====================================================================
template<typename TC>
__global__ __launch_bounds__(256) void mfma_tn(
    const bf16* __restrict__ A, const bf16* __restrict__ B, TC* __restrict__ C,
    int M, int N, int K, float* __restrict__ ps, float* __restrict__ pq)
{
    __shared__ alignas(16) unsigned short As[128 * 32];
    __shared__ alignas(16) unsigned short Bs[128 * 32];

    const int tid = threadIdx.x;
    const int l = tid & 63;
    const int nwg = gridDim.x * gridDim.y;
    int s = xcd_swz(blockIdx.y * gridDim.x + blockIdx.x, nwg);
    const int by = s / gridDim.x, bx = s % gridDim.x;
    const long m0 = (long)by * 128;
    const long n0 = (long)bx * 128;
    const int wr = (tid >> 7) & 1;
    const int wc = (tid >> 6) & 1;

    const int off0 = tid * 16;
    const int row0 = off0 >> 6;
    const int kp0  = (off0 >> 4) & 3;
    const bf16* Ag0 = A + (m0 + row0) * (long)K + kp0 * 8;
    const bf16* Ag1 = A + (m0 + row0 + 64) * (long)K + kp0 * 8;
    const bf16* Bg0 = B + (n0 + row0) * (long)K + kp0 * 8;
    const bf16* Bg1 = B + (n0 + row0 + 64) * (long)K + kp0 * 8;
    char* Asl0 = (char*)As + off0;
    char* Asl1 = (char*)As + off0 + 4096;
    char* Bsl0 = (char*)Bs + off0;
    char* Bsl1 = (char*)Bs + off0 + 4096;

    f32x4 acc[4][4];
#pragma unroll
    for (int m = 0; m < 4; ++m)
#pragma unroll
        for (int n = 0; n < 4; ++n) acc[m][n] = (f32x4){0.f, 0.f, 0.f, 0.f};

    const int fr = l & 15;
    const int fc = l >> 4;
    int aoff[4], boff[4];
#pragma unroll
    for (int m = 0; m < 4; ++m) aoff[m] = ((wr * 64 + m * 16 + fr) * 4 + fc) * 16;
#pragma unroll
    for (int n = 0; n < 4; ++n) boff[n] = ((wc * 64 + n * 16 + fr) * 4 + fc) * 16;

    for (int k0 = 0; k0 < K; k0 += 32) {
        gload_lds16(Ag0 + k0, Asl0);
        gload_lds16(Ag1 + k0, Asl1);
        gload_lds16(Bg0 + k0, Bsl0);
        gload_lds16(Bg1 + k0, Bsl1);
        __syncthreads();

        bf16x8v af[4], bfr[4];
#pragma unroll
        for (int m = 0; m < 4; ++m) af[m]  = *(const bf16x8v*)((const char*)As + aoff[m]);
#pragma unroll
        for (int n = 0; n < 4; ++n) bfr[n] = *(const bf16x8v*)((const char*)Bs + boff[n]);
#pragma unroll
        for (int m = 0; m < 4; ++m)
#pragma unroll
            for (int n = 0; n < 4; ++n)
                acc[m][n] = MFMA_BF16(af[m], bfr[n], acc[m][n], 0, 0, 0);
        __syncthreads();
    }

#pragma unroll
    for (int m = 0; m < 4; ++m) {
        long gr = m0 + wr * 64 + m * 16 + fc * 4;
#pragma unroll
        for (int n = 0; n < 4; ++n) {
            long gc = n0 + wc * 64 + n * 16 + fr;
            TC* cp = C + gr * N + gc;
#pragma unroll
            for (int r = 0; r < 4; ++r) stval(cp + (long)r * N, acc[m][n][r]);
        }
    }

    if (ps != nullptr) {
        float* red = (float*)As;
        float cs[4], cq[4];
#pragma unroll
        for (int n = 0; n < 4; ++n) {
            float s2 = 0.f, q2 = 0.f;
#pragma unroll
            for (int m = 0; m < 4; ++m)
#pragma unroll
                for (int r = 0; r < 4; ++r) {
                    float v = __bfloat162float(__float2bfloat16(acc[m][n][r]));
                    s2 += v; q2 += v * v;
                }
            s2 += __shfl_xor(s2, 16, 64); s2 += __shfl_xor(s2, 32, 64);
            q2 += __shfl_xor(q2, 16, 64); q2 += __shfl_xor(q2, 32, 64);
            cs[n] = s2; cq[n] = q2;
        }
        if (fc == 0) {
#pragma unroll
            for (int n = 0; n < 4; ++n) {
                int c = wc * 64 + n * 16 + fr;
                red[wr * 128 + c] = cs[n];
                red[256 + wr * 128 + c] = cq[n];
            }
        }
        __syncthreads();
        if (tid < 128) {
            float sv = red[tid] + red[128 + tid];
            float qv = red[256 + tid] + red[384 + tid];
            ps[(long)by * N + n0 + tid] = sv;
            pq[(long)by * N + n0 + tid] = qv;
        }
    }
}

// =====================================================================
// split-K 128x128 TN with BN-affine+ReLU fused into A staging (reg-staged
// A, per-global-k affine), f32 partials Cp[z][M][N]. XCD-swizzled.
// Serves GEMM2 (z=4) and GEMM5 (z=8).
// =====================================================================
__global__ __launch_bounds__(256) void mfma_tn_skbn(
    const bf16* __restrict__ A, const bf16* __restrict__ B, float* __restrict__ Cp,
    int M, int N, int K, int KCH, const float* __restrict__ ta, const float* __restrict__ tc)
{
    __shared__ alignas(16) unsigned short As[128 * 32];
    __shared__ alignas(16) unsigned short Bs[128 * 32];

    const int tid = threadIdx.x;
    const int l = tid & 63;
    const int gxy = gridDim.x * gridDim.y;
    const int nwg = gxy * gridDim.z;
    int s = xcd_swz((blockIdx.z * gridDim.y + blockIdx.y) * gridDim.x + blockIdx.x, nwg);
    const int bz = s / gxy;
    const int rem = s % gxy;
    const int by = rem / gridDim.x, bx = rem % gridDim.x;
    const long m0 = (long)by * 128;
    const long n0 = (long)bx * 128;
    const int wr = (tid >> 7) & 1;
    const int wc = (tid >> 6) & 1;
    const int ksrt = bz * KCH;

    const int off0 = tid * 16;
    const int row0 = off0 >> 6;
    const int kp0  = (off0 >> 4) & 3;
    const bf16* Ag0 = A + (m0 + row0) * (long)K + kp0 * 8 + ksrt;
    const bf16* Ag1 = A + (m0 + row0 + 64) * (long)K + kp0 * 8 + ksrt;
    const bf16* Bg0 = B + (n0 + row0) * (long)K + kp0 * 8 + ksrt;
    const bf16* Bg1 = B + (n0 + row0 + 64) * (long)K + kp0 * 8 + ksrt;
    char* Asl0 = (char*)As + off0;
    char* Asl1 = (char*)As + off0 + 4096;
    char* Bsl0 = (char*)Bs + off0;
    char* Bsl1 = (char*)Bs + off0 + 4096;

    f32x4 acc[4][4];
#pragma unroll
    for (int m = 0; m < 4; ++m)
#pragma unroll
        for (int n = 0; n < 4; ++n) acc[m][n] = (f32x4){0.f, 0.f, 0.f, 0.f};

    const int fr = l & 15;
    const int fc = l >> 4;
    int aoff[4], boff[4];
#pragma unroll
    for (int m = 0; m < 4; ++m) aoff[m] = ((wr * 64 + m * 16 + fr) * 4 + fc) * 16;
#pragma unroll
    for (int n = 0; n < 4; ++n) boff[n] = ((wc * 64 + n * 16 + fr) * 4 + fc) * 16;

    for (int k0 = 0; k0 < KCH; k0 += 32) {
        gload_lds16(Bg0 + k0, Bsl0);
        gload_lds16(Bg1 + k0, Bsl1);

        union { bf16 h[8]; uint4 u; } r0, r1;
        r0.u = *(const uint4*)(Ag0 + k0);
        r1.u = *(const uint4*)(Ag1 + k0);
        const int kb = ksrt + k0 + kp0 * 8;
        float4 av0 = *(const float4*)(ta + kb);
        float4 av1 = *(const float4*)(ta + kb + 4);
        float4 cv0 = *(const float4*)(tc + kb);
        float4 cv1 = *(const float4*)(tc + kb + 4);
        float av[8] = {av0.x, av0.y, av0.z, av0.w, av1.x, av1.y, av1.z, av1.w};
        float cv[8] = {cv0.x, cv0.y, cv0.z, cv0.w, cv1.x, cv1.y, cv1.z, cv1.w};
#pragma unroll
        for (int j = 0; j < 8; ++j) {
            float v = fmaxf(fmaf(av[j], __bfloat162float(r0.h[j]), cv[j]), 0.f);
            r0.h[j] = __float2bfloat16(v);
            v = fmaxf(fmaf(av[j], __bfloat162float(r1.h[j]), cv[j]), 0.f);
            r1.h[j] = __float2bfloat16(v);
        }
        *(uint4*)Asl0 = r0.u;
        *(uint4*)Asl1 = r1.u;
        __syncthreads();

        bf16x8v af[4], bfr[4];
#pragma unroll
        for (int m = 0; m < 4; ++m) af[m]  = *(const bf16x8v*)((const char*)As + aoff[m]);
#pragma unroll
        for (int n = 0; n < 4; ++n) bfr[n] = *(const bf16x8v*)((const char*)Bs + boff[n]);
#pragma unroll
        for (int m = 0; m < 4; ++m)
#pragma unroll
            for (int n = 0; n < 4; ++n)
                acc[m][n] = MFMA_BF16(af[m], bfr[n], acc[m][n], 0, 0, 0);
        __syncthreads();
    }

    float* Cb = Cp + (long)bz * M * N;
#pragma unroll
    for (int m = 0; m < 4; ++m) {
        long gr = m0 + wr * 64 + m * 16 + fc * 4;
#pragma unroll
        for (int n = 0; n < 4; ++n) {
            long gc = n0 + wc * 64 + n * 16 + fr;
            float* cp = Cb + gr * N + gc;
#pragma unroll
            for (int r = 0; r < 4; ++r) cp[(long)r * N] = acc[m][n][r];
        }
    }
}

// =====================================================================
// objin einsum as MFMA: per (b,h), C[32 t][256 c] = attnP . xP^T, K=224.
// =====================================================================
__global__ __launch_bounds__(256) void objmm_k(
    const bf16* __restrict__ attnP, const bf16* __restrict__ xP, bf16* __restrict__ objinT)
{
    __shared__ alignas(16) unsigned short As[32 * 32];
    __shared__ alignas(16) unsigned short Bs[256 * 32];
    const int tid = threadIdx.x, lane = tid & 63, wv = tid >> 6;
    const int b = blockIdx.x >> 3, h = blockIdx.x & 7;
    const bf16* Ab = attnP + ((long)(b * 256 + h * 32)) * 224;
    const bf16* Bb = xP + ((long)(b * 2048 + h * 256)) * 224;
    const int fr = lane & 15, fc = lane >> 4;
    const int srow = tid >> 2, schk = tid & 3;

    f32x4 acc[2][4];
#pragma unroll
    for (int m = 0; m < 2; ++m)
#pragma unroll
        for (int n = 0; n < 4; ++n) acc[m][n] = (f32x4){0.f, 0.f, 0.f, 0.f};

    for (int k0 = 0; k0 < 224; k0 += 32) {
        if (wv < 2)
            gload_lds16(Ab + (long)srow * 224 + schk * 8 + k0, (char*)As + tid * 16);
#pragma unroll
        for (int j = 0; j < 4; ++j)
            gload_lds16(Bb + (long)(j * 64 + srow) * 224 + schk * 8 + k0,
                        (char*)Bs + j * 4096 + tid * 16);
        __syncthreads();

        bf16x8v af[2], bfr[4];
#pragma unroll
        for (int m = 0; m < 2; ++m)
            af[m] = *(const bf16x8v*)((const char*)As + (m * 16 + fr) * 64 + fc * 16);
#pragma unroll
        for (int n = 0; n < 4; ++n)
            bfr[n] = *(const bf16x8v*)((const char*)Bs + (wv * 64 + n * 16 + fr) * 64 + fc * 16);
#pragma unroll
        for (int m = 0; m < 2; ++m)
#pragma unroll
            for (int n = 0; n < 4; ++n)
                acc[m][n] = MFMA_BF16(af[m], bfr[n], acc[m][n], 0, 0, 0);
        __syncthreads();
    }

#pragma unroll
    for (int m = 0; m < 2; ++m) {
        long gr = (long)b * 32 + m * 16 + fc * 4;
#pragma unroll
        for (int n = 0; n < 4; ++n) {
            long gc = (long)h * 256 + wv * 64 + n * 16 + fr;
            bf16* cp = objinT + gr * 2048 + gc;
#pragma unroll
            for (int r = 0; r < 4; ++r) cp[(long)r * 2048] = __float2bfloat16(acc[m][n][r]);
        }
    }
}

// ---------- fold GEMM2 split-K partials (x4) + row L2-norm; blocks >= 3136
// additionally fold the pooled-branch split-K output (merged skreduce) ----------
__global__ __launch_bounds__(256) void foldnorm_k(const float* __restrict__ p,
    float* __restrict__ z, float* __restrict__ invn,
    const float* __restrict__ skp2, float* __restrict__ out)
{
    if (blockIdx.x >= 3136) {
        int i = (blockIdx.x - 3136) * 256 + threadIdx.x;   // 16384 total
        float s = 0.f;
        for (int pz = 0; pz < 32; ++pz) s += skp2[(long)pz * 16384 + i];
        int m = i >> 6, n = i & 63;
        out[m + n * 256] = s;
        return;
    }
    int j = blockIdx.x * 4 + (threadIdx.x >> 6);
    int lane = threadIdx.x & 63;
    long off = (long)j * 256 + lane * 4;
    float4 a = *(const float4*)(p + off);
    float4 b = *(const float4*)(p + 3211264L + off);
    float4 c = *(const float4*)(p + 2 * 3211264L + off);
    float4 d = *(const float4*)(p + 3 * 3211264L + off);
    float4 s;
    s.x = (a.x + b.x) + (c.x + d.x);
    s.y = (a.y + b.y) + (c.y + d.y);
    s.z = (a.z + b.z) + (c.z + d.z);
    s.w = (a.w + b.w) + (c.w + d.w);
    *(float4*)(z + off) = s;
    float q = s.x * s.x + s.y * s.y + s.z * s.z + s.w * s.w;
#pragma unroll
    for (int off2 = 32; off2; off2 >>= 1) q += __shfl_xor(q, off2, 64);
    if (lane == 0) invn[j] = 1.f / fmaxf(sqrtf(q), 1e-12f);
}

// ---------- fold GEMM5 split-K partials (x8) + reorder -> out[b*8192+q*32+t] ----------
__global__ __launch_bounds__(256) void foldout_k(const float* __restrict__ p, float* __restrict__ out)
{
    int o = blockIdx.x * 256 + threadIdx.x;
    int b = o >> 13, rem = o & 8191, q = rem >> 5, tt = rem & 31;
    long base = ((long)(b * 32 + tt)) * 256 + q;
    float s = 0.f;
#pragma unroll
    for (int z = 0; z < 8; ++z) s += p[(long)z * 524288 + base];
    out[o] = s;
}

// =====================================================================
// merged prep: blocks [0,9216) convert the 4 weight matrices f32->bf16;
// blocks [9216, 9216+2048) pack x -> XT, xP (padded), xpT.
// =====================================================================
__global__ __launch_bounds__(256) void prep_k(
    const float* __restrict__ w1, const float* __restrict__ w2,
    const float* __restrict__ w3, const float* __restrict__ w4,
    bf16* __restrict__ o1, bf16* __restrict__ o2,
    bf16* __restrict__ o3, bf16* __restrict__ o4,
    const float* __restrict__ x, bf16* __restrict__ XT,
    bf16* __restrict__ xP, float* __restrict__ xpT)
{
    __shared__ unsigned short tile[196 * 66 + 4];
    __shared__ float pp[64];
    const int t = threadIdx.x;

    if (blockIdx.x < 9216) {
        const long L1 = 8388608, L2 = 1048576;
        long i = ((long)blockIdx.x * 256 + t) * 8;
        const float* src; bf16* dst; long e;
        if (i < L1)             { src = w1; dst = o1; e = i; }
        else if (i < L1 + L2)   { src = w2; dst = o2; e = i - L1; }
        else if (i < 2*L1 + L2) { src = w3; dst = o3; e = i - L1 - L2; }
        else                    { src = w4; dst = o4; e = i - 2*L1 - L2; }
        float4 v0 = *(const float4*)(src + e);
        float4 v1 = *(const float4*)(src + e + 4);
        union { bf16 h[8]; uint4 u; } r;
        r.h[0] = __float2bfloat16(v0.x); r.h[1] = __float2bfloat16(v0.y);
        r.h[2] = __float2bfloat16(v0.z); r.h[3] = __float2bfloat16(v0.w);
        r.h[4] = __float2bfloat16(v1.x); r.h[5] = __float2bfloat16(v1.y);
        r.h[6] = __float2bfloat16(v1.z); r.h[7] = __float2bfloat16(v1.w);
        *(uint4*)(dst + e) = r.u;
        return;
    }

    const int bid = blockIdx.x - 9216;
    const int b = bid >> 5, c0 = (bid & 31) * 64;
    const int wvi = t >> 6, lane = t & 63;

    for (int p = 0; p < 16; ++p) {
        int c = p * 4 + wvi;
        const float* row = x + ((long)b * 2048 + c0 + c) * 196;
        float v0 = row[lane];
        float v1 = row[lane + 64];
        float v2 = row[lane + 128];
        float v3 = (lane < 4) ? row[lane + 192] : 0.f;
        bf16 h0 = __float2bfloat16(v0);
        bf16 h1 = __float2bfloat16(v1);
        bf16 h2 = __float2bfloat16(v2);
        bf16 h3 = __float2bfloat16(v3);
        tile[lane * 66 + c]         = *(unsigned short*)&h0;
        tile[(lane + 64) * 66 + c]  = *(unsigned short*)&h1;
        tile[(lane + 128) * 66 + c] = *(unsigned short*)&h2;
        if (lane < 4) tile[(lane + 192) * 66 + c] = *(unsigned short*)&h3;
        float s = v0 + v1 + v2 + v3;
#pragma unroll
        for (int off = 32; off; off >>= 1) s += __shfl_xor(s, off, 64);
        if (lane == 0) pp[c] = s;
    }
    __syncthreads();
    if (t < 64) xpT[(c0 + t) * 64 + b] = pp[t] * (1.f / 196.f);

    for (int u = t; u < 196 * 8; u += 256) {
        int l = u >> 3, cc = u & 7;
        const unsigned short* sp = &tile[l * 66 + cc * 8];
        uint4 r;
        r.x = *(const unsigned int*)(sp);
        r.y = *(const unsigned int*)(sp + 2);
        r.z = *(const unsigned int*)(sp + 4);
        r.w = *(const unsigned int*)(sp + 6);
        *(uint4*)(&XT[((long)b * 196 + l) * 2048 + c0 + cc * 8]) = r;
    }

    for (int u = t; u < 64 * 28; u += 256) {
        int c = u / 28, ch = u % 28;
        int l0 = ch * 8;
        union { unsigned short h[8]; uint4 v; } r;
#pragma unroll
        for (int e = 0; e < 8; ++e) {
            int ll = l0 + e;
            r.h[e] = (ll < 196) ? tile[ll * 66 + c] : (unsigned short)0;
        }
        *(uint4*)(xP + ((long)b * 2048 + c0 + c) * 224 + l0) = r.v;
    }
}

// ---------- fold stat partials -> per-channel affine ----------
__global__ __launch_bounds__(256) void colstat2_k(const float* __restrict__ ps, const float* __restrict__ pq,
    int P, float invN, const float* __restrict__ g, const float* __restrict__ be,
    float* __restrict__ ta, float* __restrict__ tc)
{
    int c = blockIdx.x * 256 + threadIdx.x;
    float s = 0.f, q = 0.f;
    for (int p = 0; p < P; ++p) { s += ps[(long)p * 4096 + c]; q += pq[(long)p * 4096 + c]; }
    float mu  = s * invN;
    float var = q * invN - mu * mu;
    float a   = g[c] * rsqrtf(var + BN_EPS);
    ta[c] = a;
    tc[c] = be[c] - mu * a;
}

// ---------- softmax -> attnP[b*256+q][224] bf16 (zero-padded) ----------
__global__ __launch_bounds__(256) void softmax2_k(const float* __restrict__ z,
    const float* __restrict__ invn, bf16* __restrict__ attnP)
{
    int row  = blockIdx.x * 4 + (threadIdx.x >> 6);
    int lane = threadIdx.x & 63;
    int b = row >> 8, q = row & 255;
    float v[4];
    float mx = -INFINITY;
#pragma unroll
    for (int i = 0; i < 4; ++i) {
        int l = lane + 64 * i;
        if (l < 196) {
            int j = b * 196 + l;
            v[i] = z[(long)j * 256 + q] * invn[j];
        } else v[i] = -INFINITY;
        mx = fmaxf(mx, v[i]);
    }
#pragma unroll
    for (int off = 32; off; off >>= 1) mx = fmaxf(mx, __shfl_xor(mx, off, 64));
    float s = 0.f;
#pragma unroll
    for (int i = 0; i < 4; ++i) {
        v[i] = (lane + 64 * i < 196) ? __expf(v[i] - mx) : 0.f;
        s += v[i];
    }
#pragma unroll
    for (int off = 32; off; off >>= 1) s += __shfl_xor(s, off, 64);
    float is = 1.f / s;
    bf16* rp = attnP + (long)row * 224;
#pragma unroll
    for (int i = 0; i < 4; ++i) {
        int l = lane + 64 * i;
        if (l < 196) rp[l] = __float2bfloat16(v[i] * is);
        else if (l < 224) rp[l] = __float2bfloat16(0.f);
    }
}

// =====================================================================
// split-K f32 GEMM for the tiny pooled branch
// =====================================================================
template<bool TRANS>
__global__ __launch_bounds__(256) void gemmsk_k(
    const float* __restrict__ A, const float* __restrict__ B, float* __restrict__ Cp,
    int M, int N, int K, int lda, int ldbk, int KCH,
    const float* __restrict__ tra, const float* __restrict__ trc)
{
    constexpr int BM = 64, BN = 64, BK = 16;
    __shared__ float As[BK][BM + 4];
    __shared__ float Bs[BK][BN + 4];

    const int tid = threadIdx.x;
    const int m0 = blockIdx.y * BM;
    const int ks = blockIdx.z * KCH;
    const int ke = min(K, ks + KCH);

    const int tIdm = tid / 16;
    const int tIdn = tid % 16;
    const int aK  = tid % BK;
    const int aM0 = tid / BK;
    const int bN  = tid % BN;
    const int bK0 = tid / BN;

    float acc[4][4];
#pragma unroll
    for (int u = 0; u < 4; ++u)
#pragma unroll
        for (int v = 0; v < 4; ++v) acc[u][v] = 0.f;

    for (int k0 = ks; k0 < ke; k0 += BK) {
#pragma unroll
        for (int i = 0; i < 4; ++i) {
            int m = aM0 + 16 * i;
            int gk = k0 + aK, gm = m0 + m;
            float v = 0.f;
            if (gk < ke && gm < M) v = A[(long)gm * lda + gk];
            As[aK][m] = v;
        }
#pragma unroll
        for (int i = 0; i < 4; ++i) {
            int kk = bK0 + 4 * i;
            int gk = k0 + kk;
            float v = 0.f;
            if (gk < ke && bN < N) {
                v = B[(long)gk * ldbk + bN];
                if (TRANS) v = fmaxf(tra[gk] * v + trc[gk], 0.f);
            }
            Bs[kk][bN] = v;
        }
        __syncthreads();
#pragma unroll
        for (int kk = 0; kk < BK; ++kk) {
            float a[4], b[4];
#pragma unroll
            for (int u = 0; u < 4; ++u) a[u] = As[kk][tIdm * 4 + u];
#pragma unroll
            for (int v = 0; v < 4; ++v) b[v] = Bs[kk][tIdn * 4 + v];
#pragma unroll
            for (int u = 0; u < 4; ++u)
#pragma unroll
                for (int v = 0; v < 4; ++v)
                    acc[u][v] = fmaf(a[u], b[v], acc[u][v]);
        }
        __syncthreads();
    }

    float* Cb = Cp + (long)blockIdx.z * M * N;
#pragma unroll
    for (int u = 0; u < 4; ++u) {
        int gm = m0 + tIdm * 4 + u;
        if (gm >= M) continue;
#pragma unroll
        for (int v = 0; v < 4; ++v) {
            int gn = tIdn * 4 + v;
            if (gn < N) Cb[(long)gm * N + gn] = acc[u][v];
        }
    }
}

// ---------- merged split-K fold + BN stats for pooled h1 [4096][64] ----------
__global__ __launch_bounds__(256) void skbn_k(const float* __restrict__ Cp,
    const float* __restrict__ g, const float* __restrict__ be,
    float* __restrict__ h1, float* __restrict__ ta, float* __restrict__ tc)
{
    int o = blockIdx.x * 4 + (threadIdx.x >> 6);
    int b = threadIdx.x & 63;
    float s = 0.f;
#pragma unroll
    for (int p = 0; p < 16; ++p) s += Cp[(long)p * 262144 + o * 64 + b];
    h1[o * 64 + b] = s;
    float s1 = s, s2 = s * s;
#pragma unroll
    for (int off = 32; off; off >>= 1) {
        s1 += __shfl_down(s1, off, 64);
        s2 += __shfl_down(s2, off, 64);
    }
    if (b == 0) {
        float mu  = s1 * (1.f / 64.f);
        float var = s2 * (1.f / 64.f) - mu * mu;
        float a   = g[o] * rsqrtf(var + BN_EPS);
        ta[o] = a;
        tc[o] = be[o] - mu * a;
    }
}

extern "C" void kernel_launch(void* const* d_in, const int* in_sizes, int n_in,
                              void* d_out, int out_size, void* d_ws, size_t ws_size,
                              hipStream_t stream)
{
    const float* x    = (const float*)d_in[0];
    const float* pW1  = (const float*)d_in[1];
    const float* pG1  = (const float*)d_in[2];
    const float* pB1  = (const float*)d_in[3];
    const float* pW2  = (const float*)d_in[4];
    const float* ppW1 = (const float*)d_in[5];
    const float* ppG1 = (const float*)d_in[6];
    const float* ppB1 = (const float*)d_in[7];
    const float* ppW2 = (const float*)d_in[8];
    const float* poW1 = (const float*)d_in[9];
    const float* poG1 = (const float*)d_in[10];
    const float* poB1 = (const float*)d_in[11];
    const float* poW2 = (const float*)d_in[12];
    float* out = (float*)d_out;
    (void)in_sizes; (void)n_in; (void)out_size; (void)ws_size;

    char* w = (char*)d_ws;
    auto alloc = [&](size_t bytes) -> char* {
        char* p = w; w += (bytes + 255) & ~(size_t)255; return p;
    };
    bf16* ppW1b = (bf16*)alloc((size_t)4096 * 2048 * 2);
    bf16* ppW2b = (bf16*)alloc((size_t)256 * 4096 * 2);
    bf16* poW1b = (bf16*)alloc((size_t)4096 * 2048 * 2);
    bf16* poW2b = (bf16*)alloc((size_t)256 * 4096 * 2);
    char* region1 = alloc((size_t)12544 * 2048 * 2);     // XT; later skpG2/attnP/objinT/hobjT
    bf16*  XT     = (bf16*)region1;
    float* skpG2  = (float*)region1;     // 4 x 12544 x 256 x 4 == region1 size
    bf16*  attnP  = (bf16*)region1;
    bf16*  objinT = (bf16*)(region1 + 12845056);
    bf16*  hobjT  = (bf16*)(region1 + 12845056 + 8388608);
    bf16* xP     = (bf16*)alloc((size_t)64 * 2048 * 224 * 2);
    bf16* hfeatT = (bf16*)alloc((size_t)12544 * 4096 * 2);
    float* zfeatT = (float*)alloc((size_t)12544 * 256 * 4);
    float* ps    = (float*)alloc((size_t)49 * 4096 * 4);
    float* pq    = (float*)alloc((size_t)49 * 4096 * 4);
    float* invn  = (float*)alloc((size_t)12544 * 4);
    float* a2    = (float*)alloc(4096 * 4);
    float* c2    = (float*)alloc(4096 * 4);
    float* a3    = (float*)alloc(4096 * 4);
    float* c3    = (float*)alloc(4096 * 4);
    float* xpT   = (float*)alloc((size_t)2048 * 64 * 4);
    float* h1    = (float*)alloc((size_t)4096 * 64 * 4);
    float* a1    = (float*)alloc(4096 * 4);
    float* c1    = (float*)alloc(4096 * 4);
    float* skp1  = (float*)alloc((size_t)16 * 4096 * 64 * 4);
    float* skp2  = (float*)alloc((size_t)32 * 256 * 64 * 4);
    float* skp5  = (float*)alloc((size_t)8 * 2048 * 256 * 4);

    // ---- merged weight converts + input pack (one launch) ----
    prep_k<<<9216 + 2048, 256, 0, stream>>>(ppW1, ppW2, poW1, poW2,
                                            ppW1b, ppW2b, poW1b, poW2b,
                                            x, XT, xP, xpT);

    // ---- pooled branch (split-K f32, merged fold+stats) ----
    gemmsk_k<false><<<dim3(1, 64, 16), 256, 0, stream>>>(
        pW1, xpT, skp1, 4096, 64, 2048, 2048, 64, 128, nullptr, nullptr);
    skbn_k<<<1024, 256, 0, stream>>>(skp1, pG1, pB1, h1, a1, c1);
    gemmsk_k<true><<<dim3(1, 4, 32), 256, 0, stream>>>(
        pW2, h1, skp2, 256, 64, 4096, 4096, 64, 128, a1, c1);

    // ---- GEMM1 (2-phase 256^2, round-8 schedule) + fused column stats ----
    mfma_tn8<bf16><<<dim3(16, 49), 512, 0, stream>>>(XT, ppW1b, hfeatT, 12544, 4096, 2048, ps, pq);
    colstat2_k<<<16, 256, 0, stream>>>(ps, pq, 49, 1.f / 12544.f, ppG1, ppB1, a2, c2);

    // ---- GEMM2: split-K x4, fused BN+ReLU on A; fold + row-norm (+ pooled-out fold) ----
    mfma_tn_skbn<<<dim3(2, 98, 4), 256, 0, stream>>>(
        hfeatT, ppW2b, skpG2, 12544, 256, 4096, 1024, a2, c2);
    foldnorm_k<<<3136 + 64, 256, 0, stream>>>(skpG2, zfeatT, invn, skp2, out);

    // ---- softmax -> attnP ----
    softmax2_k<<<4096, 256, 0, stream>>>(zfeatT, invn, attnP);

    // ---- objin einsum via MFMA ----
    objmm_k<<<512, 256, 0, stream>>>(attnP, xP, objinT);

    // ---- GEMM4 + fused column stats ----
    mfma_tn<bf16><<<dim3(32, 16), 256, 0, stream>>>(objinT, poW1b, hobjT, 2048, 4096, 2048, ps, pq);
    colstat2_k<<<16, 256, 0, stream>>>(ps, pq, 16, 1.f / 2048.f, poG1, poB1, a3, c3);

    // ---- GEMM5 (split-K x8, fused BN+ReLU on A) + fold/reorder ----
    mfma_tn_skbn<<<dim3(2, 16, 8), 256, 0, stream>>>(
        hobjT, poW2b, skp5, 2048, 256, 4096, 512, a3, c3);
    foldout_k<<<2048, 256, 0, stream>>>(skp5, out + 16384);
}

// Round 14
// 594.642 us; speedup vs baseline: 1.0423x; 1.0094x over previous
//
#include <hip/hip_runtime.h>
#include <hip/hip_bf16.h>

using bf16 = __hip_bfloat16;
typedef __bf16 bf16x8v __attribute__((ext_vector_type(8)));
typedef float f32x4 __attribute__((ext_vector_type(4)));

#define BN_EPS 1e-5f

// ---------- dtype helpers ----------
__device__ __forceinline__ void stval(float* p, float v) { *p = v; }
__device__ __forceinline__ void stval(bf16* p, float v)  { *p = __float2bfloat16(v); }

__device__ __forceinline__ void gload_lds16(const void* g, void* l) {
    __builtin_amdgcn_global_load_lds(
        (const __attribute__((address_space(1))) unsigned int*)g,
        (__attribute__((address_space(3))) unsigned int*)l,
        16, 0, 0);
}

// bijective XCD swizzle over an arbitrary block count (m204)
__device__ __forceinline__ int xcd_swz(int orig, int nwg) {
    int q = nwg >> 3, r = nwg & 7;
    int xcd = orig & 7, idx = orig >> 3;
    return (xcd < r ? xcd * (q + 1) : r * (q + 1) + (xcd - r) * q) + idx;
}

#define MFMA_BF16 __builtin_amdgcn_mfma_f32_16x16x32_bf16

// =====================================================================
// GEMM1: 256x256 bf16 MFMA TN GEMM, 2-phase schedule (8 waves, BK=64,
// counted vmcnt(4), XOR-swizzled LDS reads, XCD swizzle) + fused
// per-column sum/sumsq partials of the bf16-rounded output.
// [round-8/10/12 verified: 229us, MfmaUtil 40%, 0 conflicts]
// =====================================================================
template<typename TC>
__global__ __launch_bounds__(512, 2) void mfma_tn8(
    const bf16* __restrict__ A, const bf16* __restrict__ B, TC* __restrict__ C,
    int M, int N, int K, float* __restrict__ ps, float* __restrict__ pq)
{
    __shared__ char lds[131072];   // 2 bufs x (A 32KB + B 32KB)
    const int NT = K >> 6;
    const int tid = threadIdx.x;
    const int lane = tid & 63;
    const int wv = tid >> 6;
    const int wm = wv >> 2;        // 0..1
    const int wn = wv & 3;         // 0..3

    // XCD swizzle (nwg % 8 == 0 here)
    const int nbx = gridDim.x;
    int flat = blockIdx.y * nbx + blockIdx.x;
    const int cpx = (nbx * gridDim.y) >> 3;
    flat = (flat & 7) * cpx + (flat >> 3);
    const int mtile = flat / nbx;
    const long m0 = (long)mtile * 256;
    const long n0 = (long)(flat % nbx) * 256;

    // staging: LDS linear; pre-swizzled global k-offset (rule 21)
    const int trow = tid >> 3;
    const int ks = (((tid & 7) ^ ((tid >> 3) & 7)) << 3);
    const bf16* Arow0 = A + (m0 + trow) * (long)K + ks;
    const bf16* Brow0 = B + (n0 + trow) * (long)K + ks;
    char* ldsA = (char*)lds + tid * 16;
    char* ldsB = (char*)lds + 32768 + tid * 16;

    auto stage_a = [&](int bbuf, int kt) {
        const bf16* g = Arow0 + ((long)kt << 6);
        char* d = ldsA + (bbuf << 16);
        gload_lds16(g, d);
        gload_lds16(g + ((long)K << 6),  d + 8192);
        gload_lds16(g + ((long)K << 7),  d + 16384);
        gload_lds16(g + 192L * (long)K,  d + 24576);
    };
    auto stage_b = [&](int bbuf, int kt) {
        const bf16* g = Brow0 + ((long)kt << 6);
        char* d = ldsB + (bbuf << 16);
        gload_lds16(g, d);
        gload_lds16(g + ((long)K << 6),  d + 8192);
        gload_lds16(g + ((long)K << 7),  d + 16384);
        gload_lds16(g + 192L * (long)K,  d + 24576);
    };

    // fragment read offsets (swizzled)
    const int fr = lane & 15, fc = lane >> 4;
    const int ca0 = ((fc ^ (fr & 7)) << 4);
    const int ca1 = (((4 + fc) ^ (fr & 7)) << 4);

    f32x4 acc[8][4];
#pragma unroll
    for (int m = 0; m < 8; ++m)
#pragma unroll
        for (int n = 0; n < 4; ++n) acc[m][n] = (f32x4){0.f, 0.f, 0.f, 0.f};

    // prologue: tiles 0 and 1
    stage_a(0, 0); stage_b(0, 0); stage_a(1, 1); stage_b(1, 1);

    for (int T = 0; T < NT; ++T) {
        const int bb = T & 1;
        const char* Ard = (const char*)lds + (bb << 16) + (wm * 128 + fr) * 128;
        const char* Brd = (const char*)lds + (bb << 16) + 32768 + (wn * 64 + fr) * 128;

        // ---- phase 0 ----
        if (T == 0)          { asm volatile("s_waitcnt vmcnt(8)" ::: "memory"); }
        else if (T < NT - 1) { asm volatile("s_waitcnt vmcnt(4)" ::: "memory"); }
        else                 { asm volatile("s_waitcnt vmcnt(0)" ::: "memory"); }
        __builtin_amdgcn_s_barrier();
        __builtin_amdgcn_sched_barrier(0);

        bf16x8v a0[8], a1[8];
#pragma unroll
        for (int m = 0; m < 8; ++m) {
            a0[m] = *(const bf16x8v*)(Ard + m * 2048 + ca0);
            a1[m] = *(const bf16x8v*)(Ard + m * 2048 + ca1);
        }
        bf16x8v b00 = *(const bf16x8v*)(Brd + ca0);
        bf16x8v b01 = *(const bf16x8v*)(Brd + ca1);
        bf16x8v b10 = *(const bf16x8v*)(Brd + 2048 + ca0);
        bf16x8v b11 = *(const bf16x8v*)(Brd + 2048 + ca1);

        if (T >= 1 && T + 1 < NT) stage_b(bb ^ 1, T + 1);

        __builtin_amdgcn_s_setprio(1);
#pragma unroll
        for (int m = 0; m < 8; ++m) {
            acc[m][0] = MFMA_BF16(a0[m], b00, acc[m][0], 0, 0, 0);
            acc[m][0] = MFMA_BF16(a1[m], b01, acc[m][0], 0, 0, 0);
            acc[m][1] = MFMA_BF16(a0[m], b10, acc[m][1], 0, 0, 0);
            acc[m][1] = MFMA_BF16(a1[m], b11, acc[m][1], 0, 0, 0);
        }
        __builtin_amdgcn_s_setprio(0);

        // ---- phase 1 ----
        __builtin_amdgcn_s_barrier();
        __builtin_amdgcn_sched_barrier(0);

        bf16x8v b20 = *(const bf16x8v*)(Brd + 2 * 2048 + ca0);
        bf16x8v b21 = *(const bf16x8v*)(Brd + 2 * 2048 + ca1);
        bf16x8v b30 = *(const bf16x8v*)(Brd + 3 * 2048 + ca0);
        bf16x8v b31 = *(const bf16x8v*)(Brd + 3 * 2048 + ca1);

        if (T + 2 < NT) stage_a(bb, T + 2);

        __builtin_amdgcn_s_setprio(1);
#pragma unroll
        for (int m = 0; m < 8; ++m) {
            acc[m][2] = MFMA_BF16(a0[m], b20, acc[m][2], 0, 0, 0);
            acc[m][2] = MFMA_BF16(a1[m], b21, acc[m][2], 0, 0, 0);
            acc[m][3] = MFMA_BF16(a0[m], b30, acc[m][3], 0, 0, 0);
            acc[m][3] = MFMA_BF16(a1[m], b31, acc[m][3], 0, 0, 0);
        }
        __builtin_amdgcn_s_setprio(0);
    }

    // epilogue: C/D layout col=lane&15, row=(lane>>4)*4+reg
#pragma unroll
    for (int m = 0; m < 8; ++m) {
        long gr = m0 + wm * 128 + m * 16 + fc * 4;
#pragma unroll
        for (int n = 0; n < 4; ++n) {
            long gc = n0 + wn * 64 + n * 16 + fr;
            TC* cp = C + gr * N + gc;
#pragma unroll
            for (int r = 0; r < 4; ++r) stval(cp + (long)r * N, acc[m][n][r]);
        }
    }

    // fused column stats (sum/sumsq of bf16-rounded values) -> ps/pq[mtile][N]
    if (ps != nullptr) {
        __syncthreads();
        float* red = (float*)lds;
        float cs[4], cq[4];
#pragma unroll
        for (int n = 0; n < 4; ++n) {
            float s = 0.f, q = 0.f;
#pragma unroll
            for (int m = 0; m < 8; ++m)
#pragma unroll
                for (int r = 0; r < 4; ++r) {
                    float v = __bfloat162float(__float2bfloat16(acc[m][n][r]));
                    s += v; q += v * v;
                }
            s += __shfl_xor(s, 16, 64); s += __shfl_xor(s, 32, 64);
            q += __shfl_xor(q, 16, 64); q += __shfl_xor(q, 32, 64);
            cs[n] = s; cq[n] = q;
        }
        if (fc == 0) {
#pragma unroll
            for (int n = 0; n < 4; ++n) {
                red[wv * 64 + n * 16 + fr] = cs[n];
                red[512 + wv * 64 + n * 16 + fr] = cq[n];
            }
        }
        __syncthreads();
        if (tid < 256) {
            int c = tid, wnn = c >> 6, idx = c & 63;
            float s = red[wnn * 64 + idx] + red[(4 + wnn) * 64 + idx];
            float q = red[512 + wnn * 64 + idx] + red[512 + (4 + wnn) * 64 + idx];
            ps[(long)mtile * N + n0 + c] = s;
            pq[(long)mtile * N + n0 + c] = q;
        }
    }
}

// =====================================================================
// GEMM4: 256x128 bf16 MFMA TN GEMM, BK=32, 8 waves (4m x 2n), 2-phase
// n-split schedule, counted vmcnt, XCD swizzle, fused column stats.
// [verified numerically as GEMM1 in round 11; used here at 256 blocks
//  = exactly 1 block/CU for M=2048,N=4096]
// =====================================================================
template<typename TC>
__global__ __launch_bounds__(512, 4) void mfma_tn8c(
    const bf16* __restrict__ A, const bf16* __restrict__ B, TC* __restrict__ C,
    int M, int N, int K, float* __restrict__ ps, float* __restrict__ pq)
{
    __shared__ alignas(16) char lds[49152];   // A: 2x16KB @0, B: 2x8KB @32768
    const int NT = K >> 5;
    const int tid = threadIdx.x;
    const int lane = tid & 63;
    const int wv = tid >> 6;
    const int wm = wv >> 1;        // 0..3
    const int wn = wv & 1;         // 0..1

    const int nbx = gridDim.x;
    int flat = blockIdx.y * nbx + blockIdx.x;
    const int cpx = (nbx * gridDim.y) >> 3;
    flat = (flat & 7) * cpx + (flat >> 3);
    const int mtile = flat / nbx;
    const long m0 = (long)mtile * 256;
    const long n0 = (long)(flat % nbx) * 128;

    const int trow = tid >> 2;
    const int tk   = (tid & 3) * 8;
    const bf16* Ar = A + (m0 + trow) * (long)K + tk;
    const bf16* Br = B + (n0 + trow) * (long)K + tk;
    char* ldsAt = (char*)lds + tid * 16;
    char* ldsBt = (char*)lds + 32768 + tid * 16;

    auto stage_a = [&](int bbuf, int kt) {
        const bf16* g = Ar + (kt << 5);
        char* d = ldsAt + bbuf * 16384;
        gload_lds16(g, d);
        gload_lds16(g + ((long)K << 7), d + 8192);
    };
    auto stage_b = [&](int bbuf, int kt) {
        gload_lds16(Br + (kt << 5), ldsBt + bbuf * 8192);
    };

    const int fr = lane & 15, fc = lane >> 4;

    f32x4 acc[4][4];
#pragma unroll
    for (int m = 0; m < 4; ++m)
#pragma unroll
        for (int n = 0; n < 4; ++n) acc[m][n] = (f32x4){0.f, 0.f, 0.f, 0.f};

    stage_a(0, 0); stage_b(0, 0); stage_a(1, 1); stage_b(1, 1);

    for (int T = 0; T < NT; ++T) {
        const int bb = T & 1;
        const char* Ard = (const char*)lds + bb * 16384 + (wm * 64 + fr) * 64 + fc * 16;
        const char* Brd = (const char*)lds + 32768 + bb * 8192 + (wn * 64 + fr) * 64 + fc * 16;

        if (T == 0)          { asm volatile("s_waitcnt vmcnt(3)" ::: "memory"); }
        else if (T < NT - 1) { asm volatile("s_waitcnt vmcnt(2)" ::: "memory"); }
        else                 { asm volatile("s_waitcnt vmcnt(0)" ::: "memory"); }
        __builtin_amdgcn_s_barrier();
        __builtin_amdgcn_sched_barrier(0);

        bf16x8v a[4];
#pragma unroll
        for (int m = 0; m < 4; ++m) a[m] = *(const bf16x8v*)(Ard + m * 1024);
        bf16x8v b0 = *(const bf16x8v*)(Brd);
        bf16x8v b1 = *(const bf16x8v*)(Brd + 1024);

        if (T >= 1 && T + 1 < NT) stage_b(bb ^ 1, T + 1);

        __builtin_amdgcn_s_setprio(1);
#pragma unroll
        for (int m = 0; m < 4; ++m) {
            acc[m][0] = MFMA_BF16(a[m], b0, acc[m][0], 0, 0, 0);
            acc[m][1] = MFMA_BF16(a[m], b1, acc[m][1], 0, 0, 0);
        }
        __builtin_amdgcn_s_setprio(0);

        __builtin_amdgcn_s_barrier();
        __builtin_amdgcn_sched_barrier(0);

        bf16x8v b2 = *(const bf16x8v*)(Brd + 2048);
        bf16x8v b3 = *(const bf16x8v*)(Brd + 3072);

        if (T + 2 < NT) stage_a(bb, T + 2);

        __builtin_amdgcn_s_setprio(1);
#pragma unroll
        for (int m = 0; m < 4; ++m) {
            acc[m][2] = MFMA_BF16(a[m], b2, acc[m][2], 0, 0, 0);
            acc[m][3] = MFMA_BF16(a[m], b3, acc[m][3], 0, 0, 0);
        }
        __builtin_amdgcn_s_setprio(0);
    }

#pragma unroll
    for (int m = 0; m < 4; ++m) {
        long gr = m0 + wm * 64 + m * 16 + fc * 4;
#pragma unroll
        for (int n = 0; n < 4; ++n) {
            long gc = n0 + wn * 64 + n * 16 + fr;
            TC* cp = C + gr * N + gc;
#pragma unroll
            for (int r = 0; r < 4; ++r) stval(cp + (long)r * N, acc[m][n][r]);
        }
    }

    if (ps != nullptr) {
        __syncthreads();
        float* red = (float*)lds;
        float cs[4], cq[4];
#pragma unroll
        for (int n = 0; n < 4; ++n) {
            float s = 0.f, q = 0.f;
#pragma unroll
            for (int m = 0; m < 4; ++m)
#pragma unroll
                for (int r = 0; r < 4; ++r) {
                    float v = __bfloat162float(__float2bfloat16(acc[m][n][r]));
                    s += v; q += v * v;
                }
            s += __shfl_xor(s, 16, 64); s += __shfl_xor(s, 32, 64);
            q += __shfl_xor(q, 16, 64); q += __shfl_xor(q, 32, 64);
            cs[n] = s; cq[n] = q;
        }
        if (fc == 0) {
#pragma unroll
            for (int n = 0; n < 4; ++n) {
                int c = wn * 64 + n * 16 + fr;
                red[wm * 128 + c] = cs[n];
                red[512 + wm * 128 + c] = cq[n];
            }
        }
        __syncthreads();
        if (tid < 128) {
            float s = red[tid] + red[128 + tid] + red[256 + tid] + red[384 + tid];
            float q = red[512 + tid] + red[640 + tid] + red[768 + tid] + red[896 + tid];
            ps[(long)mtile * N + n0 + tid] = s;
            pq[(long)mtile * N + n0 + tid] = q;
        }
    }
}

// =====================================================================
// split-K 128x128 TN with BN-affine+ReLU fused into A staging (reg-staged
// A, per-global-k affine), f32 partials Cp[z][M][N]. XCD-swizzled.
// Serves GEMM2 (z=4) and GEMM5 (z=8).
// =====================================================================
__global__ __launch_bounds__(256) void mfma_tn_skbn(
    const bf16* __restrict__ A, const bf16* __restrict__ B, float* __restrict__ Cp,
    int M, int N, int K, int KCH, const float* __restrict__ ta, const float* __restrict__ tc)
{
    __shared__ alignas(16) unsigned short As[128 * 32];
    __shared__ alignas(16) unsigned short Bs[128 * 32];

    const int tid = threadIdx.x;
    const int l = tid & 63;
    const int gxy = gridDim.x * gridDim.y;
    const int nwg = gxy * gridDim.z;
    int s = xcd_swz((blockIdx.z * gridDim.y + blockIdx.y) * gridDim.x + blockIdx.x, nwg);
    const int bz = s / gxy;
    const int rem = s % gxy;
    const int by = rem / gridDim.x, bx = rem % gridDim.x;
    const long m0 = (long)by * 128;
    const long n0 = (long)bx * 128;
    const int wr = (tid >> 7) & 1;
    const int wc = (tid >> 6) & 1;
    const int ksrt = bz * KCH;

    const int off0 = tid * 16;
    const int row0 = off0 >> 6;
    const int kp0  = (off0 >> 4) & 3;
    const bf16* Ag0 = A + (m0 + row0) * (long)K + kp0 * 8 + ksrt;
    const bf16* Ag1 = A + (m0 + row0 + 64) * (long)K + kp0 * 8 + ksrt;
    const bf16* Bg0 = B + (n0 + row0) * (long)K + kp0 * 8 + ksrt;
    const bf16* Bg1 = B + (n0 + row0 + 64) * (long)K + kp0 * 8 + ksrt;
    char* Asl0 = (char*)As + off0;
    char* Asl1 = (char*)As + off0 + 4096;
    char* Bsl0 = (char*)Bs + off0;
    char* Bsl1 = (char*)Bs + off0 + 4096;

    f32x4 acc[4][4];
#pragma unroll
    for (int m = 0; m < 4; ++m)
#pragma unroll
        for (int n = 0; n < 4; ++n) acc[m][n] = (f32x4){0.f, 0.f, 0.f, 0.f};

    const int fr = l & 15;
    const int fc = l >> 4;
    int aoff[4], boff[4];
#pragma unroll
    for (int m = 0; m < 4; ++m) aoff[m] = ((wr * 64 + m * 16 + fr) * 4 + fc) * 16;
#pragma unroll
    for (int n = 0; n < 4; ++n) boff[n] = ((wc * 64 + n * 16 + fr) * 4 + fc) * 16;

    for (int k0 = 0; k0 < KCH; k0 += 32) {
        gload_lds16(Bg0 + k0, Bsl0);
        gload_lds16(Bg1 + k0, Bsl1);

        union { bf16 h[8]; uint4 u; } r0, r1;
        r0.u = *(const uint4*)(Ag0 + k0);
        r1.u = *(const uint4*)(Ag1 + k0);
        const int kb = ksrt + k0 + kp0 * 8;
        float4 av0 = *(const float4*)(ta + kb);
        float4 av1 = *(const float4*)(ta + kb + 4);
        float4 cv0 = *(const float4*)(tc + kb);
        float4 cv1 = *(const float4*)(tc + kb + 4);
        float av[8] = {av0.x, av0.y, av0.z, av0.w, av1.x, av1.y, av1.z, av1.w};
        float cv[8] = {cv0.x, cv0.y, cv0.z, cv0.w, cv1.x, cv1.y, cv1.z, cv1.w};
#pragma unroll
        for (int j = 0; j < 8; ++j) {
            float v = fmaxf(fmaf(av[j], __bfloat162float(r0.h[j]), cv[j]), 0.f);
            r0.h[j] = __float2bfloat16(v);
            v = fmaxf(fmaf(av[j], __bfloat162float(r1.h[j]), cv[j]), 0.f);
            r1.h[j] = __float2bfloat16(v);
        }
        *(uint4*)Asl0 = r0.u;
        *(uint4*)Asl1 = r1.u;
        __syncthreads();

        bf16x8v af[4], bfr[4];
#pragma unroll
        for (int m = 0; m < 4; ++m) af[m]  = *(const bf16x8v*)((const char*)As + aoff[m]);
#pragma unroll
        for (int n = 0; n < 4; ++n) bfr[n] = *(const bf16x8v*)((const char*)Bs + boff[n]);
#pragma unroll
        for (int m = 0; m < 4; ++m)
#pragma unroll
            for (int n = 0; n < 4; ++n)
                acc[m][n] = MFMA_BF16(af[m], bfr[n], acc[m][n], 0, 0, 0);
        __syncthreads();
    }

    float* Cb = Cp + (long)bz * M * N;
#pragma unroll
    for (int m = 0; m < 4; ++m) {
        long gr = m0 + wr * 64 + m * 16 + fc * 4;
#pragma unroll
        for (int n = 0; n < 4; ++n) {
            long gc = n0 + wc * 64 + n * 16 + fr;
            float* cp = Cb + gr * N + gc;
#pragma unroll
            for (int r = 0; r < 4; ++r) cp[(long)r * N] = acc[m][n][r];
        }
    }
}

// =====================================================================
// objin einsum as MFMA: per (b,h), C[32 t][256 c] = attnP . xP^T, K=224.
// =====================================================================
__global__ __launch_bounds__(256) void objmm_k(
    const bf16* __restrict__ attnP, const bf16* __restrict__ xP, bf16* __restrict__ objinT)
{
    __shared__ alignas(16) unsigned short As[32 * 32];
    __shared__ alignas(16) unsigned short Bs[256 * 32];
    const int tid = threadIdx.x, lane = tid & 63, wv = tid >> 6;
    const int b = blockIdx.x >> 3, h = blockIdx.x & 7;
    const bf16* Ab = attnP + ((long)(b * 256 + h * 32)) * 224;
    const bf16* Bb = xP + ((long)(b * 2048 + h * 256)) * 224;
    const int fr = lane & 15, fc = lane >> 4;
    const int srow = tid >> 2, schk = tid & 3;

    f32x4 acc[2][4];
#pragma unroll
    for (int m = 0; m < 2; ++m)
#pragma unroll
        for (int n = 0; n < 4; ++n) acc[m][n] = (f32x4){0.f, 0.f, 0.f, 0.f};

    for (int k0 = 0; k0 < 224; k0 += 32) {
        if (wv < 2)
            gload_lds16(Ab + (long)srow * 224 + schk * 8 + k0, (char*)As + tid * 16);
#pragma unroll
        for (int j = 0; j < 4; ++j)
            gload_lds16(Bb + (long)(j * 64 + srow) * 224 + schk * 8 + k0,
                        (char*)Bs + j * 4096 + tid * 16);
        __syncthreads();

        bf16x8v af[2], bfr[4];
#pragma unroll
        for (int m = 0; m < 2; ++m)
            af[m] = *(const bf16x8v*)((const char*)As + (m * 16 + fr) * 64 + fc * 16);
#pragma unroll
        for (int n = 0; n < 4; ++n)
            bfr[n] = *(const bf16x8v*)((const char*)Bs + (wv * 64 + n * 16 + fr) * 64 + fc * 16);
#pragma unroll
        for (int m = 0; m < 2; ++m)
#pragma unroll
            for (int n = 0; n < 4; ++n)
                acc[m][n] = MFMA_BF16(af[m], bfr[n], acc[m][n], 0, 0, 0);
        __syncthreads();
    }

#pragma unroll
    for (int m = 0; m < 2; ++m) {
        long gr = (long)b * 32 + m * 16 + fc * 4;
#pragma unroll
        for (int n = 0; n < 4; ++n) {
            long gc = (long)h * 256 + wv * 64 + n * 16 + fr;
            bf16* cp = objinT + gr * 2048 + gc;
#pragma unroll
            for (int r = 0; r < 4; ++r) cp[(long)r * 2048] = __float2bfloat16(acc[m][n][r]);
        }
    }
}

// ---------- fold GEMM2 split-K partials (x4) + row L2-norm; blocks >= 3136
// additionally fold the pooled-branch split-K output (merged skreduce) ----------
__global__ __launch_bounds__(256) void foldnorm_k(const float* __restrict__ p,
    float* __restrict__ z, float* __restrict__ invn,
    const float* __restrict__ skp2, float* __restrict__ out)
{
    if (blockIdx.x >= 3136) {
        int i = (blockIdx.x - 3136) * 256 + threadIdx.x;   // 16384 total
        float s = 0.f;
        for (int pz = 0; pz < 32; ++pz) s += skp2[(long)pz * 16384 + i];
        int m = i >> 6, n = i & 63;
        out[m + n * 256] = s;
        return;
    }
    int j = blockIdx.x * 4 + (threadIdx.x >> 6);
    int lane = threadIdx.x & 63;
    long off = (long)j * 256 + lane * 4;
    float4 a = *(const float4*)(p + off);
    float4 b = *(const float4*)(p + 3211264L + off);
    float4 c = *(const float4*)(p + 2 * 3211264L + off);
    float4 d = *(const float4*)(p + 3 * 3211264L + off);
    float4 s;
    s.x = (a.x + b.x) + (c.x + d.x);
    s.y = (a.y + b.y) + (c.y + d.y);
    s.z = (a.z + b.z) + (c.z + d.z);
    s.w = (a.w + b.w) + (c.w + d.w);
    *(float4*)(z + off) = s;
    float q = s.x * s.x + s.y * s.y + s.z * s.z + s.w * s.w;
#pragma unroll
    for (int off2 = 32; off2; off2 >>= 1) q += __shfl_xor(q, off2, 64);
    if (lane == 0) invn[j] = 1.f / fmaxf(sqrtf(q), 1e-12f);
}

// ---------- fold GEMM5 split-K partials (x8) + reorder -> out[b*8192+q*32+t] ----------
__global__ __launch_bounds__(256) void foldout_k(const float* __restrict__ p, float* __restrict__ out)
{
    int o = blockIdx.x * 256 + threadIdx.x;
    int b = o >> 13, rem = o & 8191, q = rem >> 5, tt = rem & 31;
    long base = ((long)(b * 32 + tt)) * 256 + q;
    float s = 0.f;
#pragma unroll
    for (int z = 0; z < 8; ++z) s += p[(long)z * 524288 + base];
    out[o] = s;
}

// =====================================================================
// merged prep: blocks [0,9216) convert the 4 weight matrices f32->bf16;
// blocks [9216, 9216+2048) pack x -> XT, xP (padded), xpT.
// =====================================================================
__global__ __launch_bounds__(256) void prep_k(
    const float* __restrict__ w1, const float* __restrict__ w2,
    const float* __restrict__ w3, const float* __restrict__ w4,
    bf16* __restrict__ o1, bf16* __restrict__ o2,
    bf16* __restrict__ o3, bf16* __restrict__ o4,
    const float* __restrict__ x, bf16* __restrict__ XT,
    bf16* __restrict__ xP, float* __restrict__ xpT)
{
    __shared__ unsigned short tile[196 * 66 + 4];
    __shared__ float pp[64];
    const int t = threadIdx.x;

    if (blockIdx.x < 9216) {
        const long L1 = 8388608, L2 = 1048576;
        long i = ((long)blockIdx.x * 256 + t) * 8;
        const float* src; bf16* dst; long e;
        if (i < L1)             { src = w1; dst = o1; e = i; }
        else if (i < L1 + L2)   { src = w2; dst = o2; e = i - L1; }
        else if (i < 2*L1 + L2) { src = w3; dst = o3; e = i - L1 - L2; }
        else                    { src = w4; dst = o4; e = i - 2*L1 - L2; }
        float4 v0 = *(const float4*)(src + e);
        float4 v1 = *(const float4*)(src + e + 4);
        union { bf16 h[8]; uint4 u; } r;
        r.h[0] = __float2bfloat16(v0.x); r.h[1] = __float2bfloat16(v0.y);
        r.h[2] = __float2bfloat16(v0.z); r.h[3] = __float2bfloat16(v0.w);
        r.h[4] = __float2bfloat16(v1.x); r.h[5] = __float2bfloat16(v1.y);
        r.h[6] = __float2bfloat16(v1.z); r.h[7] = __float2bfloat16(v1.w);
        *(uint4*)(dst + e) = r.u;
        return;
    }

    const int bid = blockIdx.x - 9216;
    const int b = bid >> 5, c0 = (bid & 31) * 64;
    const int wvi = t >> 6, lane = t & 63;

    for (int p = 0; p < 16; ++p) {
        int c = p * 4 + wvi;
        const float* row = x + ((long)b * 2048 + c0 + c) * 196;
        float v0 = row[lane];
        float v1 = row[lane + 64];
        float v2 = row[lane + 128];
        float v3 = (lane < 4) ? row[lane + 192] : 0.f;
        bf16 h0 = __float2bfloat16(v0);
        bf16 h1 = __float2bfloat16(v1);
        bf16 h2 = __float2bfloat16(v2);
        bf16 h3 = __float2bfloat16(v3);
        tile[lane * 66 + c]         = *(unsigned short*)&h0;
        tile[(lane + 64) * 66 + c]  = *(unsigned short*)&h1;
        tile[(lane + 128) * 66 + c] = *(unsigned short*)&h2;
        if (lane < 4) tile[(lane + 192) * 66 + c] = *(unsigned short*)&h3;
        float s = v0 + v1 + v2 + v3;
#pragma unroll
        for (int off = 32; off; off >>= 1) s += __shfl_xor(s, off, 64);
        if (lane == 0) pp[c] = s;
    }
    __syncthreads();
    if (t < 64) xpT[(c0 + t) * 64 + b] = pp[t] * (1.f / 196.f);

    for (int u = t; u < 196 * 8; u += 256) {
        int l = u >> 3, cc = u & 7;
        const unsigned short* sp = &tile[l * 66 + cc * 8];
        uint4 r;
        r.x = *(const unsigned int*)(sp);
        r.y = *(const unsigned int*)(sp + 2);
        r.z = *(const unsigned int*)(sp + 4);
        r.w = *(const unsigned int*)(sp + 6);
        *(uint4*)(&XT[((long)b * 196 + l) * 2048 + c0 + cc * 8]) = r;
    }

    for (int u = t; u < 64 * 28; u += 256) {
        int c = u / 28, ch = u % 28;
        int l0 = ch * 8;
        union { unsigned short h[8]; uint4 v; } r;
#pragma unroll
        for (int e = 0; e < 8; ++e) {
            int ll = l0 + e;
            r.h[e] = (ll < 196) ? tile[ll * 66 + c] : (unsigned short)0;
        }
        *(uint4*)(xP + ((long)b * 2048 + c0 + c) * 224 + l0) = r.v;
    }
}

// ---------- fold stat partials -> per-channel affine ----------
__global__ __launch_bounds__(256) void colstat2_k(const float* __restrict__ ps, const float* __restrict__ pq,
    int P, float invN, const float* __restrict__ g, const float* __restrict__ be,
    float* __restrict__ ta, float* __restrict__ tc)
{
    int c = blockIdx.x * 256 + threadIdx.x;
    float s = 0.f, q = 0.f;
    for (int p = 0; p < P; ++p) { s += ps[(long)p * 4096 + c]; q += pq[(long)p * 4096 + c]; }
    float mu  = s * invN;
    float var = q * invN - mu * mu;
    float a   = g[c] * rsqrtf(var + BN_EPS);
    ta[c] = a;
    tc[c] = be[c] - mu * a;
}

// ---------- softmax -> attnP[b*256+q][224] bf16 (zero-padded) ----------
__global__ __launch_bounds__(256) void softmax2_k(const float* __restrict__ z,
    const float* __restrict__ invn, bf16* __restrict__ attnP)
{
    int row  = blockIdx.x * 4 + (threadIdx.x >> 6);
    int lane = threadIdx.x & 63;
    int b = row >> 8, q = row & 255;
    float v[4];
    float mx = -INFINITY;
#pragma unroll
    for (int i = 0; i < 4; ++i) {
        int l = lane + 64 * i;
        if (l < 196) {
            int j = b * 196 + l;
            v[i] = z[(long)j * 256 + q] * invn[j];
        } else v[i] = -INFINITY;
        mx = fmaxf(mx, v[i]);
    }
#pragma unroll
    for (int off = 32; off; off >>= 1) mx = fmaxf(mx, __shfl_xor(mx, off, 64));
    float s = 0.f;
#pragma unroll
    for (int i = 0; i < 4; ++i) {
        v[i] = (lane + 64 * i < 196) ? __expf(v[i] - mx) : 0.f;
        s += v[i];
    }
#pragma unroll
    for (int off = 32; off; off >>= 1) s += __shfl_xor(s, off, 64);
    float is = 1.f / s;
    bf16* rp = attnP + (long)row * 224;
#pragma unroll
    for (int i = 0; i < 4; ++i) {
        int l = lane + 64 * i;
        if (l < 196) rp[l] = __float2bfloat16(v[i] * is);
        else if (l < 224) rp[l] = __float2bfloat16(0.f);
    }
}

// =====================================================================
// split-K f32 GEMM for the tiny pooled branch
// =====================================================================
template<bool TRANS>
__global__ __launch_bounds__(256) void gemmsk_k(
    const float* __restrict__ A, const float* __restrict__ B, float* __restrict__ Cp,
    int M, int N, int K, int lda, int ldbk, int KCH,
    const float* __restrict__ tra, const float* __restrict__ trc)
{
    constexpr int BM = 64, BN = 64, BK = 16;
    __shared__ float As[BK][BM + 4];
    __shared__ float Bs[BK][BN + 4];

    const int tid = threadIdx.x;
    const int m0 = blockIdx.y * BM;
    const int ks = blockIdx.z * KCH;
    const int ke = min(K, ks + KCH);

    const int tIdm = tid / 16;
    const int tIdn = tid % 16;
    const int aK  = tid % BK;
    const int aM0 = tid / BK;
    const int bN  = tid % BN;
    const int bK0 = tid / BN;

    float acc[4][4];
#pragma unroll
    for (int u = 0; u < 4; ++u)
#pragma unroll
        for (int v = 0; v < 4; ++v) acc[u][v] = 0.f;

    for (int k0 = ks; k0 < ke; k0 += BK) {
#pragma unroll
        for (int i = 0; i < 4; ++i) {
            int m = aM0 + 16 * i;
            int gk = k0 + aK, gm = m0 + m;
            float v = 0.f;
            if (gk < ke && gm < M) v = A[(long)gm * lda + gk];
            As[aK][m] = v;
        }
#pragma unroll
        for (int i = 0; i < 4; ++i) {
            int kk = bK0 + 4 * i;
            int gk = k0 + kk;
            float v = 0.f;
            if (gk < ke && bN < N) {
                v = B[(long)gk * ldbk + bN];
                if (TRANS) v = fmaxf(tra[gk] * v + trc[gk], 0.f);
            }
            Bs[kk][bN] = v;
        }
        __syncthreads();
#pragma unroll
        for (int kk = 0; kk < BK; ++kk) {
            float a[4], b[4];
#pragma unroll
            for (int u = 0; u < 4; ++u) a[u] = As[kk][tIdm * 4 + u];
#pragma unroll
            for (int v = 0; v < 4; ++v) b[v] = Bs[kk][tIdn * 4 + v];
#pragma unroll
            for (int u = 0; u < 4; ++u)
#pragma unroll
                for (int v = 0; v < 4; ++v)
                    acc[u][v] = fmaf(a[u], b[v], acc[u][v]);
        }
        __syncthreads();
    }

    float* Cb = Cp + (long)blockIdx.z * M * N;
#pragma unroll
    for (int u = 0; u < 4; ++u) {
        int gm = m0 + tIdm * 4 + u;
        if (gm >= M) continue;
#pragma unroll
        for (int v = 0; v < 4; ++v) {
            int gn = tIdn * 4 + v;
            if (gn < N) Cb[(long)gm * N + gn] = acc[u][v];
        }
    }
}

// ---------- merged split-K fold + BN stats for pooled h1 [4096][64] ----------
__global__ __launch_bounds__(256) void skbn_k(const float* __restrict__ Cp,
    const float* __restrict__ g, const float* __restrict__ be,
    float* __restrict__ h1, float* __restrict__ ta, float* __restrict__ tc)
{
    int o = blockIdx.x * 4 + (threadIdx.x >> 6);
    int b = threadIdx.x & 63;
    float s = 0.f;
#pragma unroll
    for (int p = 0; p < 16; ++p) s += Cp[(long)p * 262144 + o * 64 + b];
    h1[o * 64 + b] = s;
    float s1 = s, s2 = s * s;
#pragma unroll
    for (int off = 32; off; off >>= 1) {
        s1 += __shfl_down(s1, off, 64);
        s2 += __shfl_down(s2, off, 64);
    }
    if (b == 0) {
        float mu  = s1 * (1.f / 64.f);
        float var = s2 * (1.f / 64.f) - mu * mu;
        float a   = g[o] * rsqrtf(var + BN_EPS);
        ta[o] = a;
        tc[o] = be[o] - mu * a;
    }
}

extern "C" void kernel_launch(void* const* d_in, const int* in_sizes, int n_in,
                              void* d_out, int out_size, void* d_ws, size_t ws_size,
                              hipStream_t stream)
{
    const float* x    = (const float*)d_in[0];
    const float* pW1  = (const float*)d_in[1];
    const float* pG1  = (const float*)d_in[2];
    const float* pB1  = (const float*)d_in[3];
    const float* pW2  = (const float*)d_in[4];
    const float* ppW1 = (const float*)d_in[5];
    const float* ppG1 = (const float*)d_in[6];
    const float* ppB1 = (const float*)d_in[7];
    const float* ppW2 = (const float*)d_in[8];
    const float* poW1 = (const float*)d_in[9];
    const float* poG1 = (const float*)d_in[10];
    const float* poB1 = (const float*)d_in[11];
    const float* poW2 = (const float*)d_in[12];
    float* out = (float*)d_out;
    (void)in_sizes; (void)n_in; (void)out_size; (void)ws_size;

    char* w = (char*)d_ws;
    auto alloc = [&](size_t bytes) -> char* {
        char* p = w; w += (bytes + 255) & ~(size_t)255; return p;
    };
    bf16* ppW1b = (bf16*)alloc((size_t)4096 * 2048 * 2);
    bf16* ppW2b = (bf16*)alloc((size_t)256 * 4096 * 2);
    bf16* poW1b = (bf16*)alloc((size_t)4096 * 2048 * 2);
    bf16* poW2b = (bf16*)alloc((size_t)256 * 4096 * 2);
    char* region1 = alloc((size_t)12544 * 2048 * 2);     // XT; later skpG2/attnP/objinT/hobjT
    bf16*  XT     = (bf16*)region1;
    float* skpG2  = (float*)region1;     // 4 x 12544 x 256 x 4 == region1 size
    bf16*  attnP  = (bf16*)region1;
    bf16*  objinT = (bf16*)(region1 + 12845056);
    bf16*  hobjT  = (bf16*)(region1 + 12845056 + 8388608);
    bf16* xP     = (bf16*)alloc((size_t)64 * 2048 * 224 * 2);
    bf16* hfeatT = (bf16*)alloc((size_t)12544 * 4096 * 2);
    float* zfeatT = (float*)alloc((size_t)12544 * 256 * 4);
    float* ps    = (float*)alloc((size_t)49 * 4096 * 4);
    float* pq    = (float*)alloc((size_t)49 * 4096 * 4);
    float* invn  = (float*)alloc((size_t)12544 * 4);
    float* a2    = (float*)alloc(4096 * 4);
    float* c2    = (float*)alloc(4096 * 4);
    float* a3    = (float*)alloc(4096 * 4);
    float* c3    = (float*)alloc(4096 * 4);
    float* xpT   = (float*)alloc((size_t)2048 * 64 * 4);
    float* h1    = (float*)alloc((size_t)4096 * 64 * 4);
    float* a1    = (float*)alloc(4096 * 4);
    float* c1    = (float*)alloc(4096 * 4);
    float* skp1  = (float*)alloc((size_t)16 * 4096 * 64 * 4);
    float* skp2  = (float*)alloc((size_t)32 * 256 * 64 * 4);
    float* skp5  = (float*)alloc((size_t)8 * 2048 * 256 * 4);

    // ---- merged weight converts + input pack (one launch) ----
    prep_k<<<9216 + 2048, 256, 0, stream>>>(ppW1, ppW2, poW1, poW2,
                                            ppW1b, ppW2b, poW1b, poW2b,
                                            x, XT, xP, xpT);

    // ---- pooled branch (split-K f32, merged fold+stats) ----
    gemmsk_k<false><<<dim3(1, 64, 16), 256, 0, stream>>>(
        pW1, xpT, skp1, 4096, 64, 2048, 2048, 64, 128, nullptr, nullptr);
    skbn_k<<<1024, 256, 0, stream>>>(skp1, pG1, pB1, h1, a1, c1);
    gemmsk_k<true><<<dim3(1, 4, 32), 256, 0, stream>>>(
        pW2, h1, skp2, 256, 64, 4096, 4096, 64, 128, a1, c1);

    // ---- GEMM1 (2-phase 256^2) + fused column stats ----
    mfma_tn8<bf16><<<dim3(16, 49), 512, 0, stream>>>(XT, ppW1b, hfeatT, 12544, 4096, 2048, ps, pq);
    colstat2_k<<<16, 256, 0, stream>>>(ps, pq, 49, 1.f / 12544.f, ppG1, ppB1, a2, c2);

    // ---- GEMM2: split-K x4, fused BN+ReLU on A; fold + row-norm (+ pooled-out fold) ----
    mfma_tn_skbn<<<dim3(2, 98, 4), 256, 0, stream>>>(
        hfeatT, ppW2b, skpG2, 12544, 256, 4096, 1024, a2, c2);
    foldnorm_k<<<3136 + 64, 256, 0, stream>>>(skpG2, zfeatT, invn, skp2, out);

    // ---- softmax -> attnP ----
    softmax2_k<<<4096, 256, 0, stream>>>(zfeatT, invn, attnP);

    // ---- objin einsum via MFMA ----
    objmm_k<<<512, 256, 0, stream>>>(attnP, xP, objinT);

    // ---- GEMM4 (256x128 tile, 256 blocks = 1/CU) + fused column stats ----
    mfma_tn8c<bf16><<<dim3(32, 8), 512, 0, stream>>>(objinT, poW1b, hobjT, 2048, 4096, 2048, ps, pq);
    colstat2_k<<<16, 256, 0, stream>>>(ps, pq, 8, 1.f / 2048.f, poG1, poB1, a3, c3);

    // ---- GEMM5 (split-K x8, fused BN+ReLU on A) + fold/reorder ----
    mfma_tn_skbn<<<dim3(2, 16, 8), 256, 0, stream>>>(
        hobjT, poW2b, skp5, 2048, 256, 4096, 512, a3, c3);
    foldout_k<<<2048, 256, 0, stream>>>(skp5, out + 16384);
}